// Round 20
// baseline (170.200 us; speedup 1.0000x reference)
//
#include <hip/hip_runtime.h>

typedef unsigned short ushort_t;
typedef __attribute__((ext_vector_type(8))) short bf16x8;
typedef __attribute__((ext_vector_type(4))) float f32x4;
typedef __attribute__((ext_vector_type(4))) unsigned int u32x4;
typedef __attribute__((ext_vector_type(2))) unsigned int u32x2;

#define DI static __device__ __forceinline__

DI ushort_t f2bf(float f){
  unsigned u = __builtin_bit_cast(unsigned, f);
  u += 0x7fffu + ((u >> 16) & 1u);
  return (ushort_t)(u >> 16);
}
DI float bf2f(ushort_t h){ unsigned u = ((unsigned)h) << 16; return __builtin_bit_cast(float, u); }

DI unsigned cvt_pk_bf16(float a, float b){
  unsigned r;
  asm("v_cvt_pk_bf16_f32 %0, %1, %2" : "=v"(r) : "v"(a), "v"(b));
  return r;
}

// raw v_exp_f32 (exp2) — skips libm's subnormal/range guard
DI float exp2_fast(float x){
  float r;
  asm("v_exp_f32 %0, %1" : "=v"(r) : "v"(x));
  return r;
}

DI void gload_lds16(const void* g, void* l){
  __builtin_amdgcn_global_load_lds((const __attribute__((address_space(1))) void*)g,
                                   (__attribute__((address_space(3))) void*)l, 16, 0, 0);
}

// 0.125 * log2(e): folded into Wq/bq so QK^T output is in the exp2 domain
#define CLOG2E 0.18033688011112042f

// ---------------- fused prep kernel ----------------

__global__ __launch_bounds__(256)
void prep_kernel(const float* __restrict__ x, const float* __restrict__ Wo,
                 const float* __restrict__ Wp, const float* __restrict__ Wq,
                 const float* __restrict__ Wk, const float* __restrict__ Wv,
                 const float* __restrict__ Wout,
                 const float* __restrict__ bq, const float* __restrict__ bk,
                 const float* __restrict__ bv, const int* __restrict__ mask,
                 const float* __restrict__ bo, const float* __restrict__ bout,
                 ushort_t* __restrict__ xb, ushort_t* __restrict__ WoB,
                 ushort_t* __restrict__ WpT, ushort_t* __restrict__ WqkvT,
                 ushort_t* __restrict__ WoutT, float* __restrict__ bqkv,
                 ushort_t* __restrict__ monesC, int* __restrict__ pos,
                 float* __restrict__ zbias, float* __restrict__ bcomb){
  __shared__ float tile[32][33];
  __shared__ int lds_scan[4];
  __shared__ int lds_nl;
  const int bid = blockIdx.x, tid = threadIdx.x;

  auto do_cast = [&](const float* in, ushort_t* out, int i, int n4){
    if (i >= n4) return;
    float4 v = ((const float4*)in)[i];
    ushort_t r0 = f2bf(v.x), r1 = f2bf(v.y), r2 = f2bf(v.z), r3 = f2bf(v.w);
    ushort_t* o = out + (size_t)i * 4;
    o[0] = r0; o[1] = r1; o[2] = r2; o[3] = r3;
  };
  auto do_transpose = [&](const float* src, ushort_t* dst, int R, int C,
                          int bx, int by, float scale){
    int c0 = bx * 32, r0 = by * 32;
    int tx = tid & 31, ty = tid >> 5;
    #pragma unroll
    for (int p = 0; p < 4; ++p)
      tile[ty + p * 8][tx] = src[(size_t)(r0 + ty + p * 8) * C + c0 + tx];
    __syncthreads();
    #pragma unroll
    for (int p = 0; p < 4; ++p){
      int rr = ty + p * 8;
      dst[(size_t)(c0 + rr) * R + r0 + tx] = f2bf(tile[tx][rr] * scale);
    }
  };

  if (bid < 2048){
    do_cast(x, xb, bid * 256 + tid, 524288);
  } else if (bid < 2816){
    do_cast(Wo, WoB, (bid - 2048) * 256 + tid, 196608);
  } else if (bid < 5888){
    int idx = bid - 2816;
    int w = idx / 768, r = idx % 768;
    int zz = r >> 8, t = r & 255;
    int bx = t & 15, by = t >> 4;
    if (w == 0)      do_transpose(Wp + zz * 262144, WpT + zz * 262144, 512, 512, bx, by, 1.0f);
    else if (w == 1) do_transpose(Wq + zz * 262144, WqkvT + (size_t)zz * 786432, 512, 512, bx, by, CLOG2E);
    else if (w == 2) do_transpose(Wk + zz * 262144, WqkvT + 262144 + (size_t)zz * 786432, 512, 512, bx, by, 1.0f);
    else             do_transpose(Wv + zz * 262144, WqkvT + 524288 + (size_t)zz * 786432, 512, 512, bx, by, 1.0f);
  } else if (bid < 6656){
    int t = bid - 5888;
    do_transpose(Wout, WoutT, 1536, 512, t & 15, t >> 4, 1.0f);
  } else if (bid < 6674){
    int i = (bid - 6656) * 256 + tid;
    if (i < 4608){
      int l = i / 1536, j = i % 1536;
      float v = (j < 512) ? bq[l * 512 + j] * CLOG2E
              : (j < 1024 ? bk[l * 512 + j - 512] : bv[l * 512 + j - 1024]);
      bqkv[i] = v;
    }
  } else if (bid < 6676){
    int i = (bid - 6674) * 256 + tid;
    if (i < 512) zbias[i] = 0.f;
  } else if (bid < 6804){
    int wid = tid >> 6, lane = tid & 63;
    int n = (bid - 6676) * 4 + wid;
    float s = 0.f;
    #pragma unroll
    for (int it = 0; it < 24; ++it){
      int k = it * 64 + lane;
      s += bo[k] * Wout[(size_t)k * 512 + n];
    }
    #pragma unroll
    for (int off = 32; off; off >>= 1) s += __shfl_xor(s, off);
    if (lane == 0) bcomb[n] = s + bout[n];
  } else {
    // mask scan: one block per batch b
    const int b = bid - 6804;
    int v[8]; int s8 = 0;
    #pragma unroll
    for (int i = 0; i < 8; ++i){ v[i] = mask[b * 2048 + tid * 8 + i] ? 1 : 0; s8 += v[i]; }
    const int lane = tid & 63, wid2 = tid >> 6;
    int ws = s8;
    #pragma unroll
    for (int off = 1; off < 64; off <<= 1){
      int t = __shfl_up(ws, off);
      if (lane >= off) ws += t;
    }
    if (lane == 63) lds_scan[wid2] = ws;
    __syncthreads();
    int woff = 0;
    for (int w = 0; w < wid2; ++w) woff += lds_scan[w];
    int run = woff + ws - s8;
    #pragma unroll
    for (int i = 0; i < 8; ++i){ pos[b * 2049 + tid * 8 + i] = run; run += v[i]; }
    if (tid == 255){ pos[b * 2049 + 2048] = run; lds_nl = run; }
    __syncthreads();
    const int nl = lds_nl;
    #pragma unroll
    for (int i = 0; i < 8; ++i){
      int j = tid * 8 + i;
      monesC[b * 2048 + j] = (j < nl) ? (ushort_t)0x3F80 : (ushort_t)0;
    }
  }
}

// ---------------- compaction (after qkv GEMM): V-gather + pad zeroing ----------------

__global__ __launch_bounds__(256)
void compact_kernel(const ushort_t* __restrict__ VtD, const int* __restrict__ pos,
                    ushort_t* __restrict__ KC, ushort_t* __restrict__ VtC){
  const int zb = blockIdx.y, b = zb & 1;
  const int tid = threadIdx.x;
  const int xb_ = blockIdx.x;
  if (xb_ < 128){
    const int g = xb_;                     // 0..127 -> 4 d-rows each
    const int nl = pos[b * 2049 + 2048];
    const int nt2e = ((((nl + 63) >> 6) + 1) & ~1) * 64;
    int pp[9];
    #pragma unroll
    for (int j = 0; j < 9; ++j) pp[j] = pos[b * 2049 + tid * 8 + j];
    const size_t rbase = (size_t)zb * 512 + g * 4;
    #pragma unroll
    for (int rr = 0; rr < 4; ++rr){
      const ushort_t* src = VtD + (rbase + rr) * 2048 + tid * 8;
      ushort_t* dstrow = VtC + (rbase + rr) * 2048;
      bf16x8 v = *(const bf16x8*)src;
      #pragma unroll
      for (int j = 0; j < 8; ++j)
        if (pp[j + 1] > pp[j]) dstrow[pp[j]] = (ushort_t)v[j];
      for (int ccol = nl + tid; ccol < nt2e; ccol += 256) dstrow[ccol] = 0;
    }
  } else {
    const int nl = pos[b * 2049 + 2048];
    const int nt2e = ((((nl + 63) >> 6) + 1) & ~1) * 64;
    const int padShorts = (nt2e - nl) * 512;
    bf16x8 zz = {};
    for (int j = tid * 8; j < padShorts; j += 2048)
      *(bf16x8*)(KC + ((size_t)zb * 2048 + nl) * 512 + j) = zz;
  }
}

// ---------------- GEMM core (device functions) ----------------

template<int BN>
DI void gemm_mainloop(ushort_t* __restrict__ smem,
                      const ushort_t* __restrict__ A, const ushort_t* __restrict__ Bt,
                      int K, int lda, int ldb, int n0, int m0,
                      f32x4 (&acc)[4][BN / 32]){
  constexpr int NB = BN / 32;
  ushort_t* const As = smem;
  ushort_t* const Bs = smem + 128 * 64;
  const int tid = threadIdx.x, wid = tid >> 6, lane = tid & 63;
  const int wr = wid >> 1, wc = wid & 1, lr = lane & 15, lk = lane >> 4;

  for (int k0 = 0; k0 < K; k0 += 64){
    #pragma unroll
    for (int i = 0; i < 4; ++i){
      const int chunk = i * 256 + wid * 64 + lane;
      const int row = chunk >> 3, cc = chunk & 7;
      gload_lds16(A + (size_t)(m0 + row) * lda + (k0 + cc * 8), &As[(i * 256 + wid * 64) * 8]);
    }
    #pragma unroll
    for (int i = 0; i < NB; ++i){
      const int chunk = i * 256 + wid * 64 + lane;
      const int row = chunk >> 3, cc = chunk & 7;
      gload_lds16(Bt + (size_t)(n0 + row) * ldb + (k0 + cc * 8), &Bs[(i * 256 + wid * 64) * 8]);
    }
    __syncthreads();
    bf16x8 af[4][2], bfr[NB][2];
    #pragma unroll
    for (int m = 0; m < 4; ++m){
      af[m][0] = *(const bf16x8*)&As[(wr * 64 + m * 16 + lr) * 64 + lk * 8];
      af[m][1] = *(const bf16x8*)&As[(wr * 64 + m * 16 + lr) * 64 + 32 + lk * 8];
    }
    #pragma unroll
    for (int n = 0; n < NB; ++n){
      bfr[n][0] = *(const bf16x8*)&Bs[(wc * (BN / 2) + n * 16 + lr) * 64 + lk * 8];
      bfr[n][1] = *(const bf16x8*)&Bs[(wc * (BN / 2) + n * 16 + lr) * 64 + 32 + lk * 8];
    }
    #pragma unroll
    for (int m = 0; m < 4; ++m)
      #pragma unroll
      for (int n = 0; n < NB; ++n){
        acc[m][n] = __builtin_amdgcn_mfma_f32_16x16x32_bf16(af[m][0], bfr[n][0], acc[m][n], 0, 0, 0);
        acc[m][n] = __builtin_amdgcn_mfma_f32_16x16x32_bf16(af[m][1], bfr[n][1], acc[m][n], 0, 0, 0);
      }
    __syncthreads();
  }
}

template<int BF16OUT, int BN>
DI void gemm_store(const f32x4 (&acc)[4][BN / 32], const float* __restrict__ bias,
                   void* __restrict__ Cv, int n0, int m0, int ldc){
  constexpr int NB = BN / 32;
  const int tid = threadIdx.x, wid = tid >> 6, lane = tid & 63;
  const int wr = wid >> 1, wc = wid & 1, lr = lane & 15, lk = lane >> 4;
  #pragma unroll
  for (int n = 0; n < NB; ++n){
    const int col = n0 + wc * (BN / 2) + n * 16 + lr;
    const float bv = bias[col];
    #pragma unroll
    for (int m = 0; m < 4; ++m){
      const int row0 = m0 + wr * 64 + m * 16 + lk * 4;
      #pragma unroll
      for (int j = 0; j < 4; ++j){
        const float v = acc[m][n][j] + bv;
        const size_t idx = (size_t)(row0 + j) * ldc + col;
        if (BF16OUT) ((ushort_t*)Cv)[idx] = f2bf(v);
        else         ((float*)Cv)[idx] = v;
      }
    }
  }
}

// ---------------- GEMM globals (XCD-colocated via bijective remap) ----------------
// VT=1 (qkv GEMM): Q-section -> dense QbD (ldc=512); K-section rows scattered
// directly to compacted KC (separate buffer); V-section transposed dense to VtD.

template<int BF16OUT, int BN, int VT>
__global__ __launch_bounds__(256)
void gemm_bt(const ushort_t* __restrict__ A, const ushort_t* __restrict__ Bt,
             const float* __restrict__ bias, void* __restrict__ Cv,
             int M, int N, int K, int lda, int ldb, int ldc,
             long long sA, long long sB, long long sC, long long sBias,
             ushort_t* __restrict__ VtD, ushort_t* __restrict__ KCp,
             const int* __restrict__ pos){
  constexpr int NB = BN / 32;
  __shared__ ushort_t smem[128 * 64 + BN * 64];
  const int gx = gridDim.x, gy = gridDim.y;
  const int nwg = gx * gy * gridDim.z;
  int flat = blockIdx.x + gx * (blockIdx.y + gy * blockIdx.z);
  flat = (flat & 7) * (nwg >> 3) + (flat >> 3);
  const int bxi = flat % gx;
  const int byi = (flat / gx) % gy;
  const int z   = flat / (gx * gy);

  A += (size_t)z * sA; Bt += (size_t)z * sB; bias += (size_t)z * sBias;
  const int n0 = bxi * BN, m0 = byi * 128;
  const int tid = threadIdx.x, wid = tid >> 6, lane = tid & 63;
  const int wr = wid >> 1, wc = wid & 1, lr = lane & 15, lk = lane >> 4;

  f32x4 acc[4][NB] = {};
  gemm_mainloop<BN>(smem, A, Bt, K, lda, ldb, n0, m0, acc);

  if (VT && n0 >= 1024){
    // V-section: transposed dense write to VtD via swizzled LDS bounce
    #pragma unroll
    for (int n = 0; n < NB; ++n){
      const int c = wc * (BN / 2) + n * 16 + lr;
      const float bv = bias[n0 + c];
      #pragma unroll
      for (int m = 0; m < 4; ++m){
        const int r0 = wr * 64 + m * 16 + lk * 4;
        u32x2 pk;
        pk[0] = cvt_pk_bf16(acc[m][n][0] + bv, acc[m][n][1] + bv);
        pk[1] = cvt_pk_bf16(acc[m][n][2] + bv, acc[m][n][3] + bv);
        *(u32x2*)&smem[c * 128 + (r0 ^ ((c & 7) << 3))] = pk;
      }
    }
    __syncthreads();
    constexpr int TPC = 256 / BN;
    constexpr int SPT = 128 / TPC;
    const int d_ = tid / TPC, sq = tid % TPC;
    const int gcol = n0 + d_;
    const int hh = (gcol - 1024) >> 6, dd = gcol & 63;
    const int b_ = m0 >> 11, s0g = m0 & 2047;
    ushort_t* dst = VtD + (((size_t)(z * 2 + b_) * 8 + hh) * 64 + dd) * 2048 + s0g;
    #pragma unroll
    for (int it = 0; it < SPT / 8; ++it){
      const int s0 = sq * SPT + it * 8;
      bf16x8 v = *(const bf16x8*)&smem[d_ * 128 + (s0 ^ ((d_ & 7) << 3))];
      *(bf16x8*)&dst[s0] = v;
    }
    return;
  }

  if (VT && n0 >= 512){
    // K-section: scatter live rows directly into compacted KC[zb][pos[s]][512]
    const int b_ = m0 >> 11;
    const int sbase = m0 & 2047;
    const int* posb = pos + b_ * 2049;
    ushort_t* const KCz = KCp + (size_t)(z * 2 + b_) * 2048 * 512;
    #pragma unroll
    for (int n = 0; n < NB; ++n){
      const int col = (n0 - 512) + wc * (BN / 2) + n * 16 + lr;
      const float bv = bias[n0 + wc * (BN / 2) + n * 16 + lr];
      #pragma unroll
      for (int m = 0; m < 4; ++m){
        const int s0 = sbase + wr * 64 + m * 16 + lk * 4;
        #pragma unroll
        for (int j = 0; j < 4; ++j){
          const int p0 = posb[s0 + j], p1 = posb[s0 + j + 1];
          if (p1 > p0)
            KCz[(size_t)p0 * 512 + col] = f2bf(acc[m][n][j] + bv);
        }
      }
    }
    return;
  }

  void* Cz = BF16OUT ? (void*)((ushort_t*)Cv + (size_t)z * sC)
                     : (void*)((float*)Cv + (size_t)z * sC);
  gemm_store<BF16OUT, BN>(acc, bias, Cz, n0, m0, ldc);
}

// Merged dispatch: blocks [0,96) = Wcomb GEMM; [96,864) = xl GEMM (XCD-swizzled).
// xl now stored as bf16 (halves write traffic; LN reads bf16).
__global__ __launch_bounds__(256)
void gemm_dual(const ushort_t* __restrict__ WoutT, const ushort_t* __restrict__ WoB,
               const float* __restrict__ zbias, ushort_t* __restrict__ WcombT,
               const ushort_t* __restrict__ xb, const ushort_t* __restrict__ WpT,
               const float* __restrict__ bp, ushort_t* __restrict__ xlb){
  __shared__ ushort_t smem[128 * 64 + 64 * 64];
  const int bid = blockIdx.x;
  f32x4 acc[4][2] = {};
  if (bid < 96){
    const int bx = bid & 7, by = (bid >> 3) & 3, z = bid >> 5;
    gemm_mainloop<64>(smem, WoutT + z * 512, WoB + (size_t)z * 262144,
                      512, 1536, 512, bx * 64, by * 128, acc);
    gemm_store<1, 64>(acc, zbias, WcombT + (size_t)z * 512, bx * 64, by * 128, 1536);
  } else {
    int b2 = bid - 96;
    b2 = (b2 & 7) * 96 + (b2 >> 3);
    const int bx = b2 % 24, by = b2 / 24;
    gemm_mainloop<64>(smem, xb, WpT, 512, 512, 512, bx * 64, by * 128, acc);
    gemm_store<1, 64>(acc, bp, xlb, bx * 64, by * 128, 1536);
  }
}

// ---------------- LayerNorm (bf16 input) ----------------

__global__ __launch_bounds__(256)
void ln_kernel(const ushort_t* __restrict__ xlb, ushort_t* __restrict__ xn,
               const float* __restrict__ gamma, const float* __restrict__ beta){
  int rid = blockIdx.x * 4 + (threadIdx.x >> 6);
  int lane = threadIdx.x & 63;
  int l = rid >> 12, bs = rid & 4095;
  const ushort_t* row = xlb + (size_t)bs * 1536 + l * 512;
  ushort_t* orow = xn + (size_t)bs * 1536 + l * 512;
  const bf16x8 a = *(const bf16x8*)(row + lane * 8);
  float vals[8];
  #pragma unroll
  for (int j = 0; j < 8; ++j) vals[j] = bf2f((ushort_t)a[j]);
  float s = 0.f, ss = 0.f;
  #pragma unroll
  for (int j = 0; j < 8; ++j){ s += vals[j]; ss += vals[j] * vals[j]; }
  #pragma unroll
  for (int off = 32; off; off >>= 1){
    s += __shfl_xor(s, off);
    ss += __shfl_xor(ss, off);
  }
  float mean = s * (1.0f / 512.0f);
  float var = ss * (1.0f / 512.0f) - mean * mean;
  float inv = rsqrtf(var + 1e-5f);
  const float* g = gamma + l * 512 + lane * 8;
  const float* be = beta + l * 512 + lane * 8;
  float4 g0 = ((const float4*)g)[0], g1 = ((const float4*)g)[1];
  float4 be0 = ((const float4*)be)[0], be1 = ((const float4*)be)[1];
  float gs[8] = {g0.x, g0.y, g0.z, g0.w, g1.x, g1.y, g1.z, g1.w};
  float bs8[8] = {be0.x, be0.y, be0.z, be0.w, be1.x, be1.y, be1.z, be1.w};
  bf16x8 r;
  #pragma unroll
  for (int j = 0; j < 8; ++j)
    r[j] = (short)f2bf((vals[j] - mean) * inv * gs[j] + bs8[j]);
  *(bf16x8*)(orow + lane * 8) = r;
}

// ---------------- Flash attention over COMPACTED keys ----------------
// Q from dense QbD [3][4096][512] (stride 512).

__global__ __launch_bounds__(256)
void attn_kernel(const ushort_t* __restrict__ QbD, const ushort_t* __restrict__ KC,
                 const ushort_t* __restrict__ VtC, const ushort_t* __restrict__ mones,
                 const int* __restrict__ pos, ushort_t* __restrict__ att){
  const int hz = blockIdx.x, qb = blockIdx.y;
  const int h = hz & 7, z = hz >> 3;
  const int l = z >> 1, b = z & 1;
  const ushort_t* Qb = QbD + ((size_t)l * 4096 + b * 2048) * 512 + h * 64;
  const ushort_t* Kb = KC + (size_t)z * 2048 * 512 + h * 64;      // [pad nlive][512]
  const ushort_t* Vt = VtC + ((size_t)(z * 8 + h) * 64) * 2048;   // [64 d][2048 k]

  const int nl = pos[b * 2049 + 2048];
  const int nt2 = (((nl + 63) >> 6) + 1) & ~1;

  __shared__ __attribute__((aligned(16))) ushort_t Ks[2][64 * 64];
  __shared__ __attribute__((aligned(16))) ushort_t Vs[2][64 * 64];

  const int tid = threadIdx.x, wid = tid >> 6, lane = tid & 63;
  const int lr = lane & 15, lk = lane >> 4;
  const int sw = lr & 7;
  const int qrow = qb * 64 + wid * 16 + lr;

  const ushort_t* qp = Qb + (size_t)qrow * 512 + lk * 8;
  const bf16x8 q0 = *(const bf16x8*)qp;
  const bf16x8 q1 = *(const bf16x8*)(qp + 32);

  const int ch0 = wid * 64 + lane, ch1 = 256 + wid * 64 + lane;
  const int r0_ = ch0 >> 3, c0_ = (ch0 & 7) ^ (r0_ & 7);
  const int r1_ = ch1 >> 3, c1_ = (ch1 & 7) ^ (r1_ & 7);
  const ushort_t* kg0 = Kb + (size_t)r0_ * 512 + c0_ * 8;
  const ushort_t* kg1 = Kb + (size_t)r1_ * 512 + c1_ * 8;
  const ushort_t* vg0 = Vt + (size_t)r0_ * 2048 + c0_ * 8;
  const ushort_t* vg1 = Vt + (size_t)r1_ * 2048 + c1_ * 8;
  ushort_t* const kdA0 = &Ks[0][(wid * 64) * 8];
  ushort_t* const kdA1 = &Ks[0][(256 + wid * 64) * 8];
  ushort_t* const kdB0 = &Ks[1][(wid * 64) * 8];
  ushort_t* const kdB1 = &Ks[1][(256 + wid * 64) * 8];
  ushort_t* const vdA0 = &Vs[0][(wid * 64) * 8];
  ushort_t* const vdA1 = &Vs[0][(256 + wid * 64) * 8];
  ushort_t* const vdB0 = &Vs[1][(wid * 64) * 8];
  ushort_t* const vdB1 = &Vs[1][(256 + wid * 64) * 8];

  const ushort_t* const kbA0 = &Ks[0][lr * 64 + (lk ^ sw) * 8];
  const ushort_t* const kbA4 = &Ks[0][lr * 64 + ((lk ^ sw) ^ 4) * 8];
  const ushort_t* const kbB0 = &Ks[1][lr * 64 + (lk ^ sw) * 8];
  const ushort_t* const kbB4 = &Ks[1][lr * 64 + ((lk ^ sw) ^ 4) * 8];
  const ushort_t* const vbA0 = &Vs[0][lr * 64 + (lk ^ sw) * 8];
  const ushort_t* const vbA4 = &Vs[0][lr * 64 + ((lk ^ sw) ^ 4) * 8];
  const ushort_t* const vbB0 = &Vs[1][lr * 64 + (lk ^ sw) * 8];
  const ushort_t* const vbB4 = &Vs[1][lr * 64 + ((lk ^ sw) ^ 4) * 8];

  const ushort_t* pm = mones + b * 2048 + lk * 8;

  f32x4 o[4] = {};
  f32x4 lrun = {0.f, 0.f, 0.f, 0.f};

  gload_lds16(kg0, kdA0); gload_lds16(kg1, kdA1);
  gload_lds16(vg0, vdA0); gload_lds16(vg1, vdA1);
  kg0 += 32768; kg1 += 32768; vg0 += 64; vg1 += 64;
  __syncthreads();

  auto tile_step = [&](const ushort_t* kb0, const ushort_t* kb4,
                       const ushort_t* vb0, const ushort_t* vb4,
                       ushort_t* sk0, ushort_t* sk1, ushort_t* sv0, ushort_t* sv1,
                       bool doStage){
    if (doStage){
      gload_lds16(kg0, sk0); gload_lds16(kg1, sk1);
      gload_lds16(vg0, sv0); gload_lds16(vg1, sv1);
      kg0 += 32768; kg1 += 32768; vg0 += 64; vg1 += 64;
    }
    const bf16x8 mo0 = *(const bf16x8*)pm;
    const bf16x8 mo1 = *(const bf16x8*)(pm + 32);
    pm += 64;

    f32x4 t[4];
    __builtin_amdgcn_s_setprio(1);
    #pragma unroll
    for (int hh = 0; hh < 4; ++hh){
      const bf16x8 kf0 = *(const bf16x8*)(kb0 + hh * 1024);
      const bf16x8 kf1 = *(const bf16x8*)(kb4 + hh * 1024);
      f32x4 tt = {0.f, 0.f, 0.f, 0.f};
      tt = __builtin_amdgcn_mfma_f32_16x16x32_bf16(kf0, q0, tt, 0, 0, 0);
      tt = __builtin_amdgcn_mfma_f32_16x16x32_bf16(kf1, q1, tt, 0, 0, 0);
      t[hh] = tt;
    }
    __builtin_amdgcn_s_setprio(0);

    unsigned a00, a01, a10, a11, a20, a21, a30, a31;
    a00 = cvt_pk_bf16(exp2_fast(t[0][0]), exp2_fast(t[0][1]));
    a01 = cvt_pk_bf16(exp2_fast(t[0][2]), exp2_fast(t[0][3]));
    a10 = cvt_pk_bf16(exp2_fast(t[1][0]), exp2_fast(t[1][1]));
    a11 = cvt_pk_bf16(exp2_fast(t[1][2]), exp2_fast(t[1][3]));
    a20 = cvt_pk_bf16(exp2_fast(t[2][0]), exp2_fast(t[2][1]));
    a21 = cvt_pk_bf16(exp2_fast(t[2][2]), exp2_fast(t[2][3]));
    a30 = cvt_pk_bf16(exp2_fast(t[3][0]), exp2_fast(t[3][1]));
    a31 = cvt_pk_bf16(exp2_fast(t[3][2]), exp2_fast(t[3][3]));
    asm("v_permlane32_swap_b32 %0, %1" : "+v"(a00), "+v"(a10));
    asm("v_permlane32_swap_b32 %0, %1" : "+v"(a01), "+v"(a11));
    asm("v_permlane32_swap_b32 %0, %1" : "+v"(a20), "+v"(a30));
    asm("v_permlane32_swap_b32 %0, %1" : "+v"(a21), "+v"(a31));
    asm("v_permlane16_swap_b32 %0, %1" : "+v"(a00), "+v"(a10));
    asm("v_permlane16_swap_b32 %0, %1" : "+v"(a01), "+v"(a11));
    asm("v_permlane16_swap_b32 %0, %1" : "+v"(a20), "+v"(a30));
    asm("v_permlane16_swap_b32 %0, %1" : "+v"(a21), "+v"(a31));
    const u32x4 f0 = {a00, a01, a10, a11};
    const u32x4 f1 = {a20, a21, a30, a31};
    const bf16x8 pf0 = __builtin_bit_cast(bf16x8, f0);
    const bf16x8 pf1 = __builtin_bit_cast(bf16x8, f1);

    __builtin_amdgcn_s_setprio(1);
    lrun = __builtin_amdgcn_mfma_f32_16x16x32_bf16(pf0, mo0, lrun, 0, 0, 0);
    lrun = __builtin_amdgcn_mfma_f32_16x16x32_bf16(pf1, mo1, lrun, 0, 0, 0);
    #pragma unroll
    for (int n = 0; n < 4; ++n){
      const bf16x8 v0 = *(const bf16x8*)(vb0 + n * 1024);
      const bf16x8 v1 = *(const bf16x8*)(vb4 + n * 1024);
      o[n] = __builtin_amdgcn_mfma_f32_16x16x32_bf16(pf0, v0, o[n], 0, 0, 0);
      o[n] = __builtin_amdgcn_mfma_f32_16x16x32_bf16(pf1, v1, o[n], 0, 0, 0);
    }
    __builtin_amdgcn_s_setprio(0);
    __syncthreads();
  };

  for (int kt2 = 0; kt2 < nt2; kt2 += 2){
    tile_step(kbA0, kbA4, vbA0, vbA4, kdB0, kdB1, vdB0, vdB1, true);
    tile_step(kbB0, kbB4, vbB0, vbB4, kdA0, kdA1, vdA0, vdA1, kt2 + 2 < nt2);
  }

  float invj[4];
  #pragma unroll
  for (int j = 0; j < 4; ++j) invj[j] = 1.0f / lrun[j];
  const size_t arow0 = (size_t)(b * 2048 + qb * 64 + wid * 16);
  #pragma unroll
  for (int n = 0; n < 4; ++n)
    #pragma unroll
    for (int j = 0; j < 4; ++j)
      att[(arow0 + lk * 4 + j) * 1536 + l * 512 + h * 64 + n * 16 + lr] = f2bf(o[n][j] * invj[j]);
}

// ---------------- launch ----------------

extern "C" void kernel_launch(void* const* d_in, const int* in_sizes, int n_in,
                              void* d_out, int out_size, void* d_ws, size_t ws_size,
                              hipStream_t stream){
  const float* x    = (const float*)d_in[0];
  const int*   mask = (const int*)d_in[1];
  const float* Wp   = (const float*)d_in[2];
  const float* bp   = (const float*)d_in[3];
  const float* gamma= (const float*)d_in[4];
  const float* beta = (const float*)d_in[5];
  const float* Wq   = (const float*)d_in[6];
  const float* bq   = (const float*)d_in[7];
  const float* Wk   = (const float*)d_in[8];
  const float* bk   = (const float*)d_in[9];
  const float* Wv   = (const float*)d_in[10];
  const float* bv   = (const float*)d_in[11];
  const float* Wo   = (const float*)d_in[12];
  const float* bo   = (const float*)d_in[13];
  const float* Wout = (const float*)d_in[14];
  const float* bout = (const float*)d_in[15];

  char* ws = (char*)d_ws;
  size_t off = 0;
  auto alloc = [&](size_t bytes){ void* p = ws + off; off += (bytes + 255) & ~(size_t)255; return p; };
  ushort_t* xb    = (ushort_t*)alloc(4096ull * 512 * 2);
  ushort_t* WpT   = (ushort_t*)alloc(1536ull * 512 * 2);
  ushort_t* WqkvT = (ushort_t*)alloc(3ull * 1536 * 512 * 2);
  ushort_t* WoB   = (ushort_t*)alloc(3ull * 512 * 512 * 2);
  ushort_t* WoutT = (ushort_t*)alloc(512ull * 1536 * 2);
  ushort_t* WcombT= (ushort_t*)alloc(512ull * 1536 * 2);
  float*    bqkv  = (float*)alloc(3ull * 1536 * 4);
  float*    zbias = (float*)alloc(512ull * 4);
  float*    bcomb = (float*)alloc(512ull * 4);
  ushort_t* monesC= (ushort_t*)alloc(4096ull * 2);
  int*      pos   = (int*)alloc(2ull * 2049 * 4);
  char*     xlbuf = (char*)alloc(4096ull * 1536 * 4);          // 25.17 MB scratch
  ushort_t* xn    = (ushort_t*)alloc(4096ull * 1536 * 2);
  ushort_t* QbD   = (ushort_t*)alloc(3ull * 4096 * 512 * 2);   // dense Q
  ushort_t* VtD   = (ushort_t*)alloc(6ull * 512 * 2048 * 2);   // dense V^T
  ushort_t* KC    = (ushort_t*)alloc(6ull * 2048 * 512 * 2);   // compacted K
  // xlbuf: xlb (bf16, 12.58 MB) lives until ln; then att + VtC reuse the region.
  ushort_t* xlb   = (ushort_t*)xlbuf;
  ushort_t* att   = (ushort_t*)xlbuf;
  ushort_t* VtC   = (ushort_t*)(xlbuf + 12582912);

  // fused prep (6806 blocks incl. mask scan)
  prep_kernel<<<6806, 256, 0, stream>>>(x, Wo, Wp, Wq, Wk, Wv, Wout, bq, bk, bv,
                                        mask, bo, bout,
                                        xb, WoB, WpT, WqkvT, WoutT, bqkv,
                                        monesC, pos, zbias, bcomb);

  // merged: Wcomb GEMM (96 blocks) + xl GEMM (768 blocks, XCD-swizzled, bf16 out)
  gemm_dual<<<864, 256, 0, stream>>>(WoutT, WoB, zbias, WcombT, xb, WpT, bp, xlb);

  // LayerNorm (bf16 in) -> xn bf16
  ln_kernel<<<3072, 256, 0, stream>>>(xlb, xn, gamma, beta);
  // qkv GEMM; Q -> QbD (dense), K scattered compacted -> KC, V transposed -> VtD
  gemm_bt<1, 64, 1><<<dim3(24, 32, 3), 256, 0, stream>>>(xn, WqkvT, bqkv, QbD,
      4096, 1536, 512, 1536, 512, 512, 512, 786432, 4096ll * 512, 1536,
      VtD, KC, pos);
  // V-gather live cols -> VtC; zero K/V pads (774 blocks)
  compact_kernel<<<dim3(129, 6), 256, 0, stream>>>(VtD, pos, KC, VtC);
  // flash attention over compacted keys
  attn_kernel<<<dim3(48, 32, 1), 256, 0, stream>>>(QbD, KC, VtC, monesC, pos, att);
  // out = att @ Wcomb_stack + bcomb   fp32 [4096][512]
  gemm_bt<0, 32, 0><<<dim3(16, 32, 1), 256, 0, stream>>>(att, WcombT, bcomb, (float*)d_out,
      4096, 512, 1536, 1536, 1536, 512, 0, 0, 0, 0, nullptr, nullptr, nullptr);
}

// Round 21
// 165.289 us; speedup vs baseline: 1.0297x; 1.0297x over previous
//
#include <hip/hip_runtime.h>

typedef unsigned short ushort_t;
typedef __attribute__((ext_vector_type(8))) short bf16x8;
typedef __attribute__((ext_vector_type(4))) float f32x4;
typedef __attribute__((ext_vector_type(4))) unsigned int u32x4;
typedef __attribute__((ext_vector_type(2))) unsigned int u32x2;

#define DI static __device__ __forceinline__

DI ushort_t f2bf(float f){
  unsigned u = __builtin_bit_cast(unsigned, f);
  u += 0x7fffu + ((u >> 16) & 1u);
  return (ushort_t)(u >> 16);
}
DI float bf2f(ushort_t h){ unsigned u = ((unsigned)h) << 16; return __builtin_bit_cast(float, u); }

DI unsigned cvt_pk_bf16(float a, float b){
  unsigned r;
  asm("v_cvt_pk_bf16_f32 %0, %1, %2" : "=v"(r) : "v"(a), "v"(b));
  return r;
}

// raw v_exp_f32 (exp2) — skips libm's subnormal/range guard
DI float exp2_fast(float x){
  float r;
  asm("v_exp_f32 %0, %1" : "=v"(r) : "v"(x));
  return r;
}

DI void gload_lds16(const void* g, void* l){
  __builtin_amdgcn_global_load_lds((const __attribute__((address_space(1))) void*)g,
                                   (__attribute__((address_space(3))) void*)l, 16, 0, 0);
}

// 0.125 * log2(e): folded into Wq/bq so QK^T output is in the exp2 domain
#define CLOG2E 0.18033688011112042f

// ---------------- fused prep kernel ----------------

__global__ __launch_bounds__(256)
void prep_kernel(const float* __restrict__ x, const float* __restrict__ Wo,
                 const float* __restrict__ Wp, const float* __restrict__ Wq,
                 const float* __restrict__ Wk, const float* __restrict__ Wv,
                 const float* __restrict__ Wout,
                 const float* __restrict__ bq, const float* __restrict__ bk,
                 const float* __restrict__ bv, const int* __restrict__ mask,
                 const float* __restrict__ bo, const float* __restrict__ bout,
                 ushort_t* __restrict__ xb, ushort_t* __restrict__ WoB,
                 ushort_t* __restrict__ WpT, ushort_t* __restrict__ WqkvT,
                 ushort_t* __restrict__ WoutT, float* __restrict__ bqkv,
                 ushort_t* __restrict__ monesC, int* __restrict__ pos,
                 float* __restrict__ zbias, float* __restrict__ bcomb){
  __shared__ float tile[32][33];
  __shared__ int lds_scan[4];
  __shared__ int lds_nl;
  const int bid = blockIdx.x, tid = threadIdx.x;

  auto do_cast = [&](const float* in, ushort_t* out, int i, int n4){
    if (i >= n4) return;
    float4 v = ((const float4*)in)[i];
    ushort_t r0 = f2bf(v.x), r1 = f2bf(v.y), r2 = f2bf(v.z), r3 = f2bf(v.w);
    ushort_t* o = out + (size_t)i * 4;
    o[0] = r0; o[1] = r1; o[2] = r2; o[3] = r3;
  };
  auto do_transpose = [&](const float* src, ushort_t* dst, int R, int C,
                          int bx, int by, float scale){
    int c0 = bx * 32, r0 = by * 32;
    int tx = tid & 31, ty = tid >> 5;
    #pragma unroll
    for (int p = 0; p < 4; ++p)
      tile[ty + p * 8][tx] = src[(size_t)(r0 + ty + p * 8) * C + c0 + tx];
    __syncthreads();
    #pragma unroll
    for (int p = 0; p < 4; ++p){
      int rr = ty + p * 8;
      dst[(size_t)(c0 + rr) * R + r0 + tx] = f2bf(tile[tx][rr] * scale);
    }
  };

  if (bid < 2048){
    do_cast(x, xb, bid * 256 + tid, 524288);
  } else if (bid < 2816){
    do_cast(Wo, WoB, (bid - 2048) * 256 + tid, 196608);
  } else if (bid < 5888){
    int idx = bid - 2816;
    int w = idx / 768, r = idx % 768;
    int zz = r >> 8, t = r & 255;
    int bx = t & 15, by = t >> 4;
    if (w == 0)      do_transpose(Wp + zz * 262144, WpT + zz * 262144, 512, 512, bx, by, 1.0f);
    else if (w == 1) do_transpose(Wq + zz * 262144, WqkvT + (size_t)zz * 786432, 512, 512, bx, by, CLOG2E);
    else if (w == 2) do_transpose(Wk + zz * 262144, WqkvT + 262144 + (size_t)zz * 786432, 512, 512, bx, by, 1.0f);
    else             do_transpose(Wv + zz * 262144, WqkvT + 524288 + (size_t)zz * 786432, 512, 512, bx, by, 1.0f);
  } else if (bid < 6656){
    int t = bid - 5888;
    do_transpose(Wout, WoutT, 1536, 512, t & 15, t >> 4, 1.0f);
  } else if (bid < 6674){
    int i = (bid - 6656) * 256 + tid;
    if (i < 4608){
      int l = i / 1536, j = i % 1536;
      float v = (j < 512) ? bq[l * 512 + j] * CLOG2E
              : (j < 1024 ? bk[l * 512 + j - 512] : bv[l * 512 + j - 1024]);
      bqkv[i] = v;
    }
  } else if (bid < 6676){
    int i = (bid - 6674) * 256 + tid;
    if (i < 512) zbias[i] = 0.f;
  } else if (bid < 6804){
    int wid = tid >> 6, lane = tid & 63;
    int n = (bid - 6676) * 4 + wid;
    float s = 0.f;
    #pragma unroll
    for (int it = 0; it < 24; ++it){
      int k = it * 64 + lane;
      s += bo[k] * Wout[(size_t)k * 512 + n];
    }
    #pragma unroll
    for (int off = 32; off; off >>= 1) s += __shfl_xor(s, off);
    if (lane == 0) bcomb[n] = s + bout[n];
  } else {
    // mask scan: one block per batch b
    const int b = bid - 6804;
    int v[8]; int s8 = 0;
    #pragma unroll
    for (int i = 0; i < 8; ++i){ v[i] = mask[b * 2048 + tid * 8 + i] ? 1 : 0; s8 += v[i]; }
    const int lane = tid & 63, wid2 = tid >> 6;
    int ws = s8;
    #pragma unroll
    for (int off = 1; off < 64; off <<= 1){
      int t = __shfl_up(ws, off);
      if (lane >= off) ws += t;
    }
    if (lane == 63) lds_scan[wid2] = ws;
    __syncthreads();
    int woff = 0;
    for (int w = 0; w < wid2; ++w) woff += lds_scan[w];
    int run = woff + ws - s8;
    #pragma unroll
    for (int i = 0; i < 8; ++i){ pos[b * 2049 + tid * 8 + i] = run; run += v[i]; }
    if (tid == 255){ pos[b * 2049 + 2048] = run; lds_nl = run; }
    __syncthreads();
    const int nl = lds_nl;
    #pragma unroll
    for (int i = 0; i < 8; ++i){
      int j = tid * 8 + i;
      monesC[b * 2048 + j] = (j < nl) ? (ushort_t)0x3F80 : (ushort_t)0;
    }
  }
}

// ---------------- compaction (after qkv GEMM): V-gather + pad zeroing ----------------

__global__ __launch_bounds__(256)
void compact_kernel(const ushort_t* __restrict__ VtD, const int* __restrict__ pos,
                    ushort_t* __restrict__ KC, ushort_t* __restrict__ VtC){
  const int zb = blockIdx.y, b = zb & 1;
  const int tid = threadIdx.x;
  const int xb_ = blockIdx.x;
  if (xb_ < 128){
    const int g = xb_;                     // 0..127 -> 4 d-rows each
    const int nl = pos[b * 2049 + 2048];
    const int nt2e = ((((nl + 63) >> 6) + 1) & ~1) * 64;
    int pp[9];
    #pragma unroll
    for (int j = 0; j < 9; ++j) pp[j] = pos[b * 2049 + tid * 8 + j];
    const size_t rbase = (size_t)zb * 512 + g * 4;
    #pragma unroll
    for (int rr = 0; rr < 4; ++rr){
      const ushort_t* src = VtD + (rbase + rr) * 2048 + tid * 8;
      ushort_t* dstrow = VtC + (rbase + rr) * 2048;
      bf16x8 v = *(const bf16x8*)src;
      #pragma unroll
      for (int j = 0; j < 8; ++j)
        if (pp[j + 1] > pp[j]) dstrow[pp[j]] = (ushort_t)v[j];
      for (int ccol = nl + tid; ccol < nt2e; ccol += 256) dstrow[ccol] = 0;
    }
  } else {
    const int nl = pos[b * 2049 + 2048];
    const int nt2e = ((((nl + 63) >> 6) + 1) & ~1) * 64;
    const int padShorts = (nt2e - nl) * 512;
    bf16x8 zz = {};
    for (int j = tid * 8; j < padShorts; j += 2048)
      *(bf16x8*)(KC + ((size_t)zb * 2048 + nl) * 512 + j) = zz;
  }
}

// ---------------- GEMM core (device functions) ----------------

template<int BN>
DI void gemm_mainloop(ushort_t* __restrict__ smem,
                      const ushort_t* __restrict__ A, const ushort_t* __restrict__ Bt,
                      int K, int lda, int ldb, int n0, int m0,
                      f32x4 (&acc)[4][BN / 32]){
  constexpr int NB = BN / 32;
  ushort_t* const As = smem;
  ushort_t* const Bs = smem + 128 * 64;
  const int tid = threadIdx.x, wid = tid >> 6, lane = tid & 63;
  const int wr = wid >> 1, wc = wid & 1, lr = lane & 15, lk = lane >> 4;

  for (int k0 = 0; k0 < K; k0 += 64){
    #pragma unroll
    for (int i = 0; i < 4; ++i){
      const int chunk = i * 256 + wid * 64 + lane;
      const int row = chunk >> 3, cc = chunk & 7;
      gload_lds16(A + (size_t)(m0 + row) * lda + (k0 + cc * 8), &As[(i * 256 + wid * 64) * 8]);
    }
    #pragma unroll
    for (int i = 0; i < NB; ++i){
      const int chunk = i * 256 + wid * 64 + lane;
      const int row = chunk >> 3, cc = chunk & 7;
      gload_lds16(Bt + (size_t)(n0 + row) * ldb + (k0 + cc * 8), &Bs[(i * 256 + wid * 64) * 8]);
    }
    __syncthreads();
    bf16x8 af[4][2], bfr[NB][2];
    #pragma unroll
    for (int m = 0; m < 4; ++m){
      af[m][0] = *(const bf16x8*)&As[(wr * 64 + m * 16 + lr) * 64 + lk * 8];
      af[m][1] = *(const bf16x8*)&As[(wr * 64 + m * 16 + lr) * 64 + 32 + lk * 8];
    }
    #pragma unroll
    for (int n = 0; n < NB; ++n){
      bfr[n][0] = *(const bf16x8*)&Bs[(wc * (BN / 2) + n * 16 + lr) * 64 + lk * 8];
      bfr[n][1] = *(const bf16x8*)&Bs[(wc * (BN / 2) + n * 16 + lr) * 64 + 32 + lk * 8];
    }
    #pragma unroll
    for (int m = 0; m < 4; ++m)
      #pragma unroll
      for (int n = 0; n < NB; ++n){
        acc[m][n] = __builtin_amdgcn_mfma_f32_16x16x32_bf16(af[m][0], bfr[n][0], acc[m][n], 0, 0, 0);
        acc[m][n] = __builtin_amdgcn_mfma_f32_16x16x32_bf16(af[m][1], bfr[n][1], acc[m][n], 0, 0, 0);
      }
    __syncthreads();
  }
}

template<int BF16OUT, int BN>
DI void gemm_store(const f32x4 (&acc)[4][BN / 32], const float* __restrict__ bias,
                   void* __restrict__ Cv, int n0, int m0, int ldc){
  constexpr int NB = BN / 32;
  const int tid = threadIdx.x, wid = tid >> 6, lane = tid & 63;
  const int wr = wid >> 1, wc = wid & 1, lr = lane & 15, lk = lane >> 4;
  #pragma unroll
  for (int n = 0; n < NB; ++n){
    const int col = n0 + wc * (BN / 2) + n * 16 + lr;
    const float bv = bias[col];
    #pragma unroll
    for (int m = 0; m < 4; ++m){
      const int row0 = m0 + wr * 64 + m * 16 + lk * 4;
      #pragma unroll
      for (int j = 0; j < 4; ++j){
        const float v = acc[m][n][j] + bv;
        const size_t idx = (size_t)(row0 + j) * ldc + col;
        if (BF16OUT) ((ushort_t*)Cv)[idx] = f2bf(v);
        else         ((float*)Cv)[idx] = v;
      }
    }
  }
}

// ---------------- GEMM globals (XCD-colocated via bijective remap) ----------------
// VT=1 (qkv GEMM): Q-section -> dense QbD (ldc=512); K-section rows packed via
// LDS bounce then VECTOR-scattered to compacted KC; V-section transposed to VtD.

template<int BF16OUT, int BN, int VT>
__global__ __launch_bounds__(256)
void gemm_bt(const ushort_t* __restrict__ A, const ushort_t* __restrict__ Bt,
             const float* __restrict__ bias, void* __restrict__ Cv,
             int M, int N, int K, int lda, int ldb, int ldc,
             long long sA, long long sB, long long sC, long long sBias,
             ushort_t* __restrict__ VtD, ushort_t* __restrict__ KCp,
             const int* __restrict__ pos){
  constexpr int NB = BN / 32;
  __shared__ ushort_t smem[128 * 64 + BN * 64];
  const int gx = gridDim.x, gy = gridDim.y;
  const int nwg = gx * gy * gridDim.z;
  int flat = blockIdx.x + gx * (blockIdx.y + gy * blockIdx.z);
  flat = (flat & 7) * (nwg >> 3) + (flat >> 3);
  const int bxi = flat % gx;
  const int byi = (flat / gx) % gy;
  const int z   = flat / (gx * gy);

  A += (size_t)z * sA; Bt += (size_t)z * sB; bias += (size_t)z * sBias;
  const int n0 = bxi * BN, m0 = byi * 128;
  const int tid = threadIdx.x, wid = tid >> 6, lane = tid & 63;
  const int wr = wid >> 1, wc = wid & 1, lr = lane & 15, lk = lane >> 4;

  f32x4 acc[4][NB] = {};
  gemm_mainloop<BN>(smem, A, Bt, K, lda, ldb, n0, m0, acc);

  if (VT && n0 >= 1024){
    // V-section: transposed dense write to VtD via swizzled LDS bounce
    #pragma unroll
    for (int n = 0; n < NB; ++n){
      const int c = wc * (BN / 2) + n * 16 + lr;
      const float bv = bias[n0 + c];
      #pragma unroll
      for (int m = 0; m < 4; ++m){
        const int r0 = wr * 64 + m * 16 + lk * 4;
        u32x2 pk;
        pk[0] = cvt_pk_bf16(acc[m][n][0] + bv, acc[m][n][1] + bv);
        pk[1] = cvt_pk_bf16(acc[m][n][2] + bv, acc[m][n][3] + bv);
        *(u32x2*)&smem[c * 128 + (r0 ^ ((c & 7) << 3))] = pk;
      }
    }
    __syncthreads();
    constexpr int TPC = 256 / BN;
    constexpr int SPT = 128 / TPC;
    const int d_ = tid / TPC, sq = tid % TPC;
    const int gcol = n0 + d_;
    const int hh = (gcol - 1024) >> 6, dd = gcol & 63;
    const int b_ = m0 >> 11, s0g = m0 & 2047;
    ushort_t* dst = VtD + (((size_t)(z * 2 + b_) * 8 + hh) * 64 + dd) * 2048 + s0g;
    #pragma unroll
    for (int it = 0; it < SPT / 8; ++it){
      const int s0 = sq * SPT + it * 8;
      bf16x8 v = *(const bf16x8*)&smem[d_ * 128 + (s0 ^ ((d_ & 7) << 3))];
      *(bf16x8*)&dst[s0] = v;
    }
    return;
  }

  if (VT && n0 >= 512){
    // K-section: pack [128 r][64 c] bf16 into LDS, then vector-scatter live
    // rows (16B chunks) into compacted KC[zb][pos[s]][512].
    #pragma unroll
    for (int n = 0; n < NB; ++n){
      const int c = wc * (BN / 2) + n * 16 + lr;
      const float bv = bias[n0 + c];
      #pragma unroll
      for (int m = 0; m < 4; ++m){
        const int r0 = wr * 64 + m * 16 + lk * 4;
        #pragma unroll
        for (int j = 0; j < 4; ++j)
          smem[(r0 + j) * 64 + c] = f2bf(acc[m][n][j] + bv);
      }
    }
    __syncthreads();
    const int b_ = m0 >> 11;
    const int sbase = m0 & 2047;
    const int* posb = pos + b_ * 2049;
    ushort_t* const KCz = KCp + (size_t)(z * 2 + b_) * 2048 * 512;
    const int col0 = n0 - 512;
    #pragma unroll
    for (int it = 0; it < 4; ++it){
      const int idx = it * 256 + tid;        // 0..1023
      const int r = idx >> 3, cc8 = idx & 7;
      const int p0 = posb[sbase + r], p1 = posb[sbase + r + 1];
      if (p1 > p0){
        const bf16x8 v = *(const bf16x8*)&smem[r * 64 + cc8 * 8];
        *(bf16x8*)&KCz[(size_t)p0 * 512 + col0 + cc8 * 8] = v;
      }
    }
    return;
  }

  void* Cz = BF16OUT ? (void*)((ushort_t*)Cv + (size_t)z * sC)
                     : (void*)((float*)Cv + (size_t)z * sC);
  gemm_store<BF16OUT, BN>(acc, bias, Cz, n0, m0, ldc);
}

// Merged dispatch: blocks [0,96) = Wcomb GEMM; [96,864) = xl GEMM (XCD-swizzled).
// xl stored as bf16 (halves write traffic; LN reads bf16).
__global__ __launch_bounds__(256)
void gemm_dual(const ushort_t* __restrict__ WoutT, const ushort_t* __restrict__ WoB,
               const float* __restrict__ zbias, ushort_t* __restrict__ WcombT,
               const ushort_t* __restrict__ xb, const ushort_t* __restrict__ WpT,
               const float* __restrict__ bp, ushort_t* __restrict__ xlb){
  __shared__ ushort_t smem[128 * 64 + 64 * 64];
  const int bid = blockIdx.x;
  f32x4 acc[4][2] = {};
  if (bid < 96){
    const int bx = bid & 7, by = (bid >> 3) & 3, z = bid >> 5;
    gemm_mainloop<64>(smem, WoutT + z * 512, WoB + (size_t)z * 262144,
                      512, 1536, 512, bx * 64, by * 128, acc);
    gemm_store<1, 64>(acc, zbias, WcombT + (size_t)z * 512, bx * 64, by * 128, 1536);
  } else {
    int b2 = bid - 96;
    b2 = (b2 & 7) * 96 + (b2 >> 3);
    const int bx = b2 % 24, by = b2 / 24;
    gemm_mainloop<64>(smem, xb, WpT, 512, 512, 512, bx * 64, by * 128, acc);
    gemm_store<1, 64>(acc, bp, xlb, bx * 64, by * 128, 1536);
  }
}

// ---------------- LayerNorm (bf16 input) ----------------

__global__ __launch_bounds__(256)
void ln_kernel(const ushort_t* __restrict__ xlb, ushort_t* __restrict__ xn,
               const float* __restrict__ gamma, const float* __restrict__ beta){
  int rid = blockIdx.x * 4 + (threadIdx.x >> 6);
  int lane = threadIdx.x & 63;
  int l = rid >> 12, bs = rid & 4095;
  const ushort_t* row = xlb + (size_t)bs * 1536 + l * 512;
  ushort_t* orow = xn + (size_t)bs * 1536 + l * 512;
  const bf16x8 a = *(const bf16x8*)(row + lane * 8);
  float vals[8];
  #pragma unroll
  for (int j = 0; j < 8; ++j) vals[j] = bf2f((ushort_t)a[j]);
  float s = 0.f, ss = 0.f;
  #pragma unroll
  for (int j = 0; j < 8; ++j){ s += vals[j]; ss += vals[j] * vals[j]; }
  #pragma unroll
  for (int off = 32; off; off >>= 1){
    s += __shfl_xor(s, off);
    ss += __shfl_xor(ss, off);
  }
  float mean = s * (1.0f / 512.0f);
  float var = ss * (1.0f / 512.0f) - mean * mean;
  float inv = rsqrtf(var + 1e-5f);
  const float* g = gamma + l * 512 + lane * 8;
  const float* be = beta + l * 512 + lane * 8;
  float4 g0 = ((const float4*)g)[0], g1 = ((const float4*)g)[1];
  float4 be0 = ((const float4*)be)[0], be1 = ((const float4*)be)[1];
  float gs[8] = {g0.x, g0.y, g0.z, g0.w, g1.x, g1.y, g1.z, g1.w};
  float bs8[8] = {be0.x, be0.y, be0.z, be0.w, be1.x, be1.y, be1.z, be1.w};
  bf16x8 r;
  #pragma unroll
  for (int j = 0; j < 8; ++j)
    r[j] = (short)f2bf((vals[j] - mean) * inv * gs[j] + bs8[j]);
  *(bf16x8*)(orow + lane * 8) = r;
}

// ---------------- Flash attention over COMPACTED keys ----------------
// Q from dense QbD [3][4096][512] (stride 512).

__global__ __launch_bounds__(256)
void attn_kernel(const ushort_t* __restrict__ QbD, const ushort_t* __restrict__ KC,
                 const ushort_t* __restrict__ VtC, const ushort_t* __restrict__ mones,
                 const int* __restrict__ pos, ushort_t* __restrict__ att){
  const int hz = blockIdx.x, qb = blockIdx.y;
  const int h = hz & 7, z = hz >> 3;
  const int l = z >> 1, b = z & 1;
  const ushort_t* Qb = QbD + ((size_t)l * 4096 + b * 2048) * 512 + h * 64;
  const ushort_t* Kb = KC + (size_t)z * 2048 * 512 + h * 64;      // [pad nlive][512]
  const ushort_t* Vt = VtC + ((size_t)(z * 8 + h) * 64) * 2048;   // [64 d][2048 k]

  const int nl = pos[b * 2049 + 2048];
  const int nt2 = (((nl + 63) >> 6) + 1) & ~1;

  __shared__ __attribute__((aligned(16))) ushort_t Ks[2][64 * 64];
  __shared__ __attribute__((aligned(16))) ushort_t Vs[2][64 * 64];

  const int tid = threadIdx.x, wid = tid >> 6, lane = tid & 63;
  const int lr = lane & 15, lk = lane >> 4;
  const int sw = lr & 7;
  const int qrow = qb * 64 + wid * 16 + lr;

  const ushort_t* qp = Qb + (size_t)qrow * 512 + lk * 8;
  const bf16x8 q0 = *(const bf16x8*)qp;
  const bf16x8 q1 = *(const bf16x8*)(qp + 32);

  const int ch0 = wid * 64 + lane, ch1 = 256 + wid * 64 + lane;
  const int r0_ = ch0 >> 3, c0_ = (ch0 & 7) ^ (r0_ & 7);
  const int r1_ = ch1 >> 3, c1_ = (ch1 & 7) ^ (r1_ & 7);
  const ushort_t* kg0 = Kb + (size_t)r0_ * 512 + c0_ * 8;
  const ushort_t* kg1 = Kb + (size_t)r1_ * 512 + c1_ * 8;
  const ushort_t* vg0 = Vt + (size_t)r0_ * 2048 + c0_ * 8;
  const ushort_t* vg1 = Vt + (size_t)r1_ * 2048 + c1_ * 8;
  ushort_t* const kdA0 = &Ks[0][(wid * 64) * 8];
  ushort_t* const kdA1 = &Ks[0][(256 + wid * 64) * 8];
  ushort_t* const kdB0 = &Ks[1][(wid * 64) * 8];
  ushort_t* const kdB1 = &Ks[1][(256 + wid * 64) * 8];
  ushort_t* const vdA0 = &Vs[0][(wid * 64) * 8];
  ushort_t* const vdA1 = &Vs[0][(256 + wid * 64) * 8];
  ushort_t* const vdB0 = &Vs[1][(wid * 64) * 8];
  ushort_t* const vdB1 = &Vs[1][(256 + wid * 64) * 8];

  const ushort_t* const kbA0 = &Ks[0][lr * 64 + (lk ^ sw) * 8];
  const ushort_t* const kbA4 = &Ks[0][lr * 64 + ((lk ^ sw) ^ 4) * 8];
  const ushort_t* const kbB0 = &Ks[1][lr * 64 + (lk ^ sw) * 8];
  const ushort_t* const kbB4 = &Ks[1][lr * 64 + ((lk ^ sw) ^ 4) * 8];
  const ushort_t* const vbA0 = &Vs[0][lr * 64 + (lk ^ sw) * 8];
  const ushort_t* const vbA4 = &Vs[0][lr * 64 + ((lk ^ sw) ^ 4) * 8];
  const ushort_t* const vbB0 = &Vs[1][lr * 64 + (lk ^ sw) * 8];
  const ushort_t* const vbB4 = &Vs[1][lr * 64 + ((lk ^ sw) ^ 4) * 8];

  const ushort_t* pm = mones + b * 2048 + lk * 8;

  f32x4 o[4] = {};
  f32x4 lrun = {0.f, 0.f, 0.f, 0.f};

  gload_lds16(kg0, kdA0); gload_lds16(kg1, kdA1);
  gload_lds16(vg0, vdA0); gload_lds16(vg1, vdA1);
  kg0 += 32768; kg1 += 32768; vg0 += 64; vg1 += 64;
  __syncthreads();

  auto tile_step = [&](const ushort_t* kb0, const ushort_t* kb4,
                       const ushort_t* vb0, const ushort_t* vb4,
                       ushort_t* sk0, ushort_t* sk1, ushort_t* sv0, ushort_t* sv1,
                       bool doStage){
    if (doStage){
      gload_lds16(kg0, sk0); gload_lds16(kg1, sk1);
      gload_lds16(vg0, sv0); gload_lds16(vg1, sv1);
      kg0 += 32768; kg1 += 32768; vg0 += 64; vg1 += 64;
    }
    const bf16x8 mo0 = *(const bf16x8*)pm;
    const bf16x8 mo1 = *(const bf16x8*)(pm + 32);
    pm += 64;

    f32x4 t[4];
    __builtin_amdgcn_s_setprio(1);
    #pragma unroll
    for (int hh = 0; hh < 4; ++hh){
      const bf16x8 kf0 = *(const bf16x8*)(kb0 + hh * 1024);
      const bf16x8 kf1 = *(const bf16x8*)(kb4 + hh * 1024);
      f32x4 tt = {0.f, 0.f, 0.f, 0.f};
      tt = __builtin_amdgcn_mfma_f32_16x16x32_bf16(kf0, q0, tt, 0, 0, 0);
      tt = __builtin_amdgcn_mfma_f32_16x16x32_bf16(kf1, q1, tt, 0, 0, 0);
      t[hh] = tt;
    }
    __builtin_amdgcn_s_setprio(0);

    unsigned a00, a01, a10, a11, a20, a21, a30, a31;
    a00 = cvt_pk_bf16(exp2_fast(t[0][0]), exp2_fast(t[0][1]));
    a01 = cvt_pk_bf16(exp2_fast(t[0][2]), exp2_fast(t[0][3]));
    a10 = cvt_pk_bf16(exp2_fast(t[1][0]), exp2_fast(t[1][1]));
    a11 = cvt_pk_bf16(exp2_fast(t[1][2]), exp2_fast(t[1][3]));
    a20 = cvt_pk_bf16(exp2_fast(t[2][0]), exp2_fast(t[2][1]));
    a21 = cvt_pk_bf16(exp2_fast(t[2][2]), exp2_fast(t[2][3]));
    a30 = cvt_pk_bf16(exp2_fast(t[3][0]), exp2_fast(t[3][1]));
    a31 = cvt_pk_bf16(exp2_fast(t[3][2]), exp2_fast(t[3][3]));
    asm("v_permlane32_swap_b32 %0, %1" : "+v"(a00), "+v"(a10));
    asm("v_permlane32_swap_b32 %0, %1" : "+v"(a01), "+v"(a11));
    asm("v_permlane32_swap_b32 %0, %1" : "+v"(a20), "+v"(a30));
    asm("v_permlane32_swap_b32 %0, %1" : "+v"(a21), "+v"(a31));
    asm("v_permlane16_swap_b32 %0, %1" : "+v"(a00), "+v"(a10));
    asm("v_permlane16_swap_b32 %0, %1" : "+v"(a01), "+v"(a11));
    asm("v_permlane16_swap_b32 %0, %1" : "+v"(a20), "+v"(a30));
    asm("v_permlane16_swap_b32 %0, %1" : "+v"(a21), "+v"(a31));
    const u32x4 f0 = {a00, a01, a10, a11};
    const u32x4 f1 = {a20, a21, a30, a31};
    const bf16x8 pf0 = __builtin_bit_cast(bf16x8, f0);
    const bf16x8 pf1 = __builtin_bit_cast(bf16x8, f1);

    __builtin_amdgcn_s_setprio(1);
    lrun = __builtin_amdgcn_mfma_f32_16x16x32_bf16(pf0, mo0, lrun, 0, 0, 0);
    lrun = __builtin_amdgcn_mfma_f32_16x16x32_bf16(pf1, mo1, lrun, 0, 0, 0);
    #pragma unroll
    for (int n = 0; n < 4; ++n){
      const bf16x8 v0 = *(const bf16x8*)(vb0 + n * 1024);
      const bf16x8 v1 = *(const bf16x8*)(vb4 + n * 1024);
      o[n] = __builtin_amdgcn_mfma_f32_16x16x32_bf16(pf0, v0, o[n], 0, 0, 0);
      o[n] = __builtin_amdgcn_mfma_f32_16x16x32_bf16(pf1, v1, o[n], 0, 0, 0);
    }
    __builtin_amdgcn_s_setprio(0);
    __syncthreads();
  };

  for (int kt2 = 0; kt2 < nt2; kt2 += 2){
    tile_step(kbA0, kbA4, vbA0, vbA4, kdB0, kdB1, vdB0, vdB1, true);
    tile_step(kbB0, kbB4, vbB0, vbB4, kdA0, kdA1, vdA0, vdA1, kt2 + 2 < nt2);
  }

  float invj[4];
  #pragma unroll
  for (int j = 0; j < 4; ++j) invj[j] = 1.0f / lrun[j];
  const size_t arow0 = (size_t)(b * 2048 + qb * 64 + wid * 16);
  #pragma unroll
  for (int n = 0; n < 4; ++n)
    #pragma unroll
    for (int j = 0; j < 4; ++j)
      att[(arow0 + lk * 4 + j) * 1536 + l * 512 + h * 64 + n * 16 + lr] = f2bf(o[n][j] * invj[j]);
}

// ---------------- launch ----------------

extern "C" void kernel_launch(void* const* d_in, const int* in_sizes, int n_in,
                              void* d_out, int out_size, void* d_ws, size_t ws_size,
                              hipStream_t stream){
  const float* x    = (const float*)d_in[0];
  const int*   mask = (const int*)d_in[1];
  const float* Wp   = (const float*)d_in[2];
  const float* bp   = (const float*)d_in[3];
  const float* gamma= (const float*)d_in[4];
  const float* beta = (const float*)d_in[5];
  const float* Wq   = (const float*)d_in[6];
  const float* bq   = (const float*)d_in[7];
  const float* Wk   = (const float*)d_in[8];
  const float* bk   = (const float*)d_in[9];
  const float* Wv   = (const float*)d_in[10];
  const float* bv   = (const float*)d_in[11];
  const float* Wo   = (const float*)d_in[12];
  const float* bo   = (const float*)d_in[13];
  const float* Wout = (const float*)d_in[14];
  const float* bout = (const float*)d_in[15];

  char* ws = (char*)d_ws;
  size_t off = 0;
  auto alloc = [&](size_t bytes){ void* p = ws + off; off += (bytes + 255) & ~(size_t)255; return p; };
  ushort_t* xb    = (ushort_t*)alloc(4096ull * 512 * 2);
  ushort_t* WpT   = (ushort_t*)alloc(1536ull * 512 * 2);
  ushort_t* WqkvT = (ushort_t*)alloc(3ull * 1536 * 512 * 2);
  ushort_t* WoB   = (ushort_t*)alloc(3ull * 512 * 512 * 2);
  ushort_t* WoutT = (ushort_t*)alloc(512ull * 1536 * 2);
  ushort_t* WcombT= (ushort_t*)alloc(512ull * 1536 * 2);
  float*    bqkv  = (float*)alloc(3ull * 1536 * 4);
  float*    zbias = (float*)alloc(512ull * 4);
  float*    bcomb = (float*)alloc(512ull * 4);
  ushort_t* monesC= (ushort_t*)alloc(4096ull * 2);
  int*      pos   = (int*)alloc(2ull * 2049 * 4);
  char*     xlbuf = (char*)alloc(4096ull * 1536 * 4);          // 25.17 MB scratch
  ushort_t* xn    = (ushort_t*)alloc(4096ull * 1536 * 2);
  ushort_t* QbD   = (ushort_t*)alloc(3ull * 4096 * 512 * 2);   // dense Q
  ushort_t* VtD   = (ushort_t*)alloc(6ull * 512 * 2048 * 2);   // dense V^T
  ushort_t* KC    = (ushort_t*)alloc(6ull * 2048 * 512 * 2);   // compacted K
  // xlbuf: xlb (bf16, 12.58 MB) lives until ln; then att + VtC reuse the region.
  ushort_t* xlb   = (ushort_t*)xlbuf;
  ushort_t* att   = (ushort_t*)xlbuf;
  ushort_t* VtC   = (ushort_t*)(xlbuf + 12582912);

  // fused prep (6806 blocks incl. mask scan)
  prep_kernel<<<6806, 256, 0, stream>>>(x, Wo, Wp, Wq, Wk, Wv, Wout, bq, bk, bv,
                                        mask, bo, bout,
                                        xb, WoB, WpT, WqkvT, WoutT, bqkv,
                                        monesC, pos, zbias, bcomb);

  // merged: Wcomb GEMM (96 blocks) + xl GEMM (768 blocks, XCD-swizzled, bf16 out)
  gemm_dual<<<864, 256, 0, stream>>>(WoutT, WoB, zbias, WcombT, xb, WpT, bp, xlb);

  // LayerNorm (bf16 in) -> xn bf16
  ln_kernel<<<3072, 256, 0, stream>>>(xlb, xn, gamma, beta);
  // qkv GEMM; Q -> QbD (dense), K vector-scattered compacted -> KC, V -> VtD
  gemm_bt<1, 64, 1><<<dim3(24, 32, 3), 256, 0, stream>>>(xn, WqkvT, bqkv, QbD,
      4096, 1536, 512, 1536, 512, 512, 512, 786432, 4096ll * 512, 1536,
      VtD, KC, pos);
  // V-gather live cols -> VtC; zero K/V pads (774 blocks)
  compact_kernel<<<dim3(129, 6), 256, 0, stream>>>(VtD, pos, KC, VtC);
  // flash attention over compacted keys
  attn_kernel<<<dim3(48, 32, 1), 256, 0, stream>>>(QbD, KC, VtC, monesC, pos, att);
  // out = att @ Wcomb_stack + bcomb   fp32 [4096][512]
  gemm_bt<0, 32, 0><<<dim3(16, 32, 1), 256, 0, stream>>>(att, WcombT, bcomb, (float*)d_out,
      4096, 512, 1536, 1536, 1536, 512, 0, 0, 0, 0, nullptr, nullptr, nullptr);
}

// Round 22
// 159.534 us; speedup vs baseline: 1.0669x; 1.0361x over previous
//
#include <hip/hip_runtime.h>

typedef unsigned short ushort_t;
typedef __attribute__((ext_vector_type(8))) short bf16x8;
typedef __attribute__((ext_vector_type(4))) float f32x4;
typedef __attribute__((ext_vector_type(4))) unsigned int u32x4;
typedef __attribute__((ext_vector_type(2))) unsigned int u32x2;

#define DI static __device__ __forceinline__

DI ushort_t f2bf(float f){
  unsigned u = __builtin_bit_cast(unsigned, f);
  u += 0x7fffu + ((u >> 16) & 1u);
  return (ushort_t)(u >> 16);
}
DI float bf2f(ushort_t h){ unsigned u = ((unsigned)h) << 16; return __builtin_bit_cast(float, u); }

DI unsigned cvt_pk_bf16(float a, float b){
  unsigned r;
  asm("v_cvt_pk_bf16_f32 %0, %1, %2" : "=v"(r) : "v"(a), "v"(b));
  return r;
}

// raw v_exp_f32 (exp2) — skips libm's subnormal/range guard
DI float exp2_fast(float x){
  float r;
  asm("v_exp_f32 %0, %1" : "=v"(r) : "v"(x));
  return r;
}

DI void gload_lds16(const void* g, void* l){
  __builtin_amdgcn_global_load_lds((const __attribute__((address_space(1))) void*)g,
                                   (__attribute__((address_space(3))) void*)l, 16, 0, 0);
}

// 0.125 * log2(e): folded into Wq/bq so QK^T output is in the exp2 domain
#define CLOG2E 0.18033688011112042f

// shared helpers ------------------------------------------------------------

DI void do_cast_seg(const float* __restrict__ in, ushort_t* __restrict__ out,
                    int i, int n4){
  if (i >= n4) return;
  float4 v = ((const float4*)in)[i];
  ushort_t r0 = f2bf(v.x), r1 = f2bf(v.y), r2 = f2bf(v.z), r3 = f2bf(v.w);
  ushort_t* o = out + (size_t)i * 4;
  o[0] = r0; o[1] = r1; o[2] = r2; o[3] = r3;
}

DI void do_transpose_seg(float* __restrict__ tile,  // [32][33] floats
                         const float* __restrict__ src, ushort_t* __restrict__ dst,
                         int R, int C, int bx, int by, float scale, int tid){
  int c0 = bx * 32, r0 = by * 32;
  int tx = tid & 31, ty = tid >> 5;
  #pragma unroll
  for (int p = 0; p < 4; ++p)
    tile[(ty + p * 8) * 33 + tx] = src[(size_t)(r0 + ty + p * 8) * C + c0 + tx];
  __syncthreads();
  #pragma unroll
  for (int p = 0; p < 4; ++p){
    int rr = ty + p * 8;
    dst[(size_t)(c0 + rr) * R + r0 + tx] = f2bf(tile[tx * 33 + rr] * scale);
  }
}

// ---------------- prep-A: only what gemm_dual needs ----------------
// [0,2048) cast x | [2048,2816) cast Wo | [2816,3584) transpose Wp
// [3584,4352) transpose Wout | [4352,4354) zbias

__global__ __launch_bounds__(256)
void prep_kernel(const float* __restrict__ x, const float* __restrict__ Wo,
                 const float* __restrict__ Wp, const float* __restrict__ Wout,
                 ushort_t* __restrict__ xb, ushort_t* __restrict__ WoB,
                 ushort_t* __restrict__ WpT, ushort_t* __restrict__ WoutT,
                 float* __restrict__ zbias){
  __shared__ float tile[32 * 33];
  const int bid = blockIdx.x, tid = threadIdx.x;
  if (bid < 2048){
    do_cast_seg(x, xb, bid * 256 + tid, 524288);
  } else if (bid < 2816){
    do_cast_seg(Wo, WoB, (bid - 2048) * 256 + tid, 196608);
  } else if (bid < 3584){
    int r = bid - 2816;
    int zz = r >> 8, t = r & 255;
    do_transpose_seg(tile, Wp + zz * 262144, WpT + zz * 262144, 512, 512,
                     t & 15, t >> 4, 1.0f, tid);
  } else if (bid < 4352){
    int t = bid - 3584;
    do_transpose_seg(tile, Wout, WoutT, 1536, 512, t & 15, t >> 4, 1.0f, tid);
  } else {
    int i = (bid - 4352) * 256 + tid;
    if (i < 512) zbias[i] = 0.f;
  }
}

// ---------------- compaction (after qkv GEMM): V-gather + pad zeroing ----------------

__global__ __launch_bounds__(256)
void compact_kernel(const ushort_t* __restrict__ VtD, const int* __restrict__ pos,
                    ushort_t* __restrict__ KC, ushort_t* __restrict__ VtC){
  const int zb = blockIdx.y, b = zb & 1;
  const int tid = threadIdx.x;
  const int xb_ = blockIdx.x;
  if (xb_ < 128){
    const int g = xb_;                     // 0..127 -> 4 d-rows each
    const int nl = pos[b * 2049 + 2048];
    const int nt2e = ((((nl + 63) >> 6) + 1) & ~1) * 64;
    int pp[9];
    #pragma unroll
    for (int j = 0; j < 9; ++j) pp[j] = pos[b * 2049 + tid * 8 + j];
    const size_t rbase = (size_t)zb * 512 + g * 4;
    #pragma unroll
    for (int rr = 0; rr < 4; ++rr){
      const ushort_t* src = VtD + (rbase + rr) * 2048 + tid * 8;
      ushort_t* dstrow = VtC + (rbase + rr) * 2048;
      bf16x8 v = *(const bf16x8*)src;
      #pragma unroll
      for (int j = 0; j < 8; ++j)
        if (pp[j + 1] > pp[j]) dstrow[pp[j]] = (ushort_t)v[j];
      for (int ccol = nl + tid; ccol < nt2e; ccol += 256) dstrow[ccol] = 0;
    }
  } else {
    const int nl = pos[b * 2049 + 2048];
    const int nt2e = ((((nl + 63) >> 6) + 1) & ~1) * 64;
    const int padShorts = (nt2e - nl) * 512;
    bf16x8 zz = {};
    for (int j = tid * 8; j < padShorts; j += 2048)
      *(bf16x8*)(KC + ((size_t)zb * 2048 + nl) * 512 + j) = zz;
  }
}

// ---------------- GEMM core (device functions) ----------------

template<int BN>
DI void gemm_mainloop(ushort_t* __restrict__ smem,
                      const ushort_t* __restrict__ A, const ushort_t* __restrict__ Bt,
                      int K, int lda, int ldb, int n0, int m0,
                      f32x4 (&acc)[4][BN / 32]){
  constexpr int NB = BN / 32;
  ushort_t* const As = smem;
  ushort_t* const Bs = smem + 128 * 64;
  const int tid = threadIdx.x, wid = tid >> 6, lane = tid & 63;
  const int wr = wid >> 1, wc = wid & 1, lr = lane & 15, lk = lane >> 4;

  for (int k0 = 0; k0 < K; k0 += 64){
    #pragma unroll
    for (int i = 0; i < 4; ++i){
      const int chunk = i * 256 + wid * 64 + lane;
      const int row = chunk >> 3, cc = chunk & 7;
      gload_lds16(A + (size_t)(m0 + row) * lda + (k0 + cc * 8), &As[(i * 256 + wid * 64) * 8]);
    }
    #pragma unroll
    for (int i = 0; i < NB; ++i){
      const int chunk = i * 256 + wid * 64 + lane;
      const int row = chunk >> 3, cc = chunk & 7;
      gload_lds16(Bt + (size_t)(n0 + row) * ldb + (k0 + cc * 8), &Bs[(i * 256 + wid * 64) * 8]);
    }
    __syncthreads();
    bf16x8 af[4][2], bfr[NB][2];
    #pragma unroll
    for (int m = 0; m < 4; ++m){
      af[m][0] = *(const bf16x8*)&As[(wr * 64 + m * 16 + lr) * 64 + lk * 8];
      af[m][1] = *(const bf16x8*)&As[(wr * 64 + m * 16 + lr) * 64 + 32 + lk * 8];
    }
    #pragma unroll
    for (int n = 0; n < NB; ++n){
      bfr[n][0] = *(const bf16x8*)&Bs[(wc * (BN / 2) + n * 16 + lr) * 64 + lk * 8];
      bfr[n][1] = *(const bf16x8*)&Bs[(wc * (BN / 2) + n * 16 + lr) * 64 + 32 + lk * 8];
    }
    #pragma unroll
    for (int m = 0; m < 4; ++m)
      #pragma unroll
      for (int n = 0; n < NB; ++n){
        acc[m][n] = __builtin_amdgcn_mfma_f32_16x16x32_bf16(af[m][0], bfr[n][0], acc[m][n], 0, 0, 0);
        acc[m][n] = __builtin_amdgcn_mfma_f32_16x16x32_bf16(af[m][1], bfr[n][1], acc[m][n], 0, 0, 0);
      }
    __syncthreads();
  }
}

template<int BF16OUT, int BN>
DI void gemm_store(const f32x4 (&acc)[4][BN / 32], const float* __restrict__ bias,
                   void* __restrict__ Cv, int n0, int m0, int ldc){
  constexpr int NB = BN / 32;
  const int tid = threadIdx.x, wid = tid >> 6, lane = tid & 63;
  const int wr = wid >> 1, wc = wid & 1, lr = lane & 15, lk = lane >> 4;
  #pragma unroll
  for (int n = 0; n < NB; ++n){
    const int col = n0 + wc * (BN / 2) + n * 16 + lr;
    const float bv = bias[col];
    #pragma unroll
    for (int m = 0; m < 4; ++m){
      const int row0 = m0 + wr * 64 + m * 16 + lk * 4;
      #pragma unroll
      for (int j = 0; j < 4; ++j){
        const float v = acc[m][n][j] + bv;
        const size_t idx = (size_t)(row0 + j) * ldc + col;
        if (BF16OUT) ((ushort_t*)Cv)[idx] = f2bf(v);
        else         ((float*)Cv)[idx] = v;
      }
    }
  }
}

// ---------------- GEMM globals (XCD-colocated via bijective remap) ----------------
// VT=1 (qkv GEMM): Q-section -> dense QbD (ldc=512); K-section rows packed via
// LDS bounce then VECTOR-scattered to compacted KC; V-section transposed to VtD.

template<int BF16OUT, int BN, int VT>
__global__ __launch_bounds__(256)
void gemm_bt(const ushort_t* __restrict__ A, const ushort_t* __restrict__ Bt,
             const float* __restrict__ bias, void* __restrict__ Cv,
             int M, int N, int K, int lda, int ldb, int ldc,
             long long sA, long long sB, long long sC, long long sBias,
             ushort_t* __restrict__ VtD, ushort_t* __restrict__ KCp,
             const int* __restrict__ pos){
  constexpr int NB = BN / 32;
  __shared__ ushort_t smem[128 * 64 + BN * 64];
  const int gx = gridDim.x, gy = gridDim.y;
  const int nwg = gx * gy * gridDim.z;
  int flat = blockIdx.x + gx * (blockIdx.y + gy * blockIdx.z);
  flat = (flat & 7) * (nwg >> 3) + (flat >> 3);
  const int bxi = flat % gx;
  const int byi = (flat / gx) % gy;
  const int z   = flat / (gx * gy);

  A += (size_t)z * sA; Bt += (size_t)z * sB; bias += (size_t)z * sBias;
  const int n0 = bxi * BN, m0 = byi * 128;
  const int tid = threadIdx.x, wid = tid >> 6, lane = tid & 63;
  const int wr = wid >> 1, wc = wid & 1, lr = lane & 15, lk = lane >> 4;

  f32x4 acc[4][NB] = {};
  gemm_mainloop<BN>(smem, A, Bt, K, lda, ldb, n0, m0, acc);

  if (VT && n0 >= 1024){
    // V-section: transposed dense write to VtD via swizzled LDS bounce
    #pragma unroll
    for (int n = 0; n < NB; ++n){
      const int c = wc * (BN / 2) + n * 16 + lr;
      const float bv = bias[n0 + c];
      #pragma unroll
      for (int m = 0; m < 4; ++m){
        const int r0 = wr * 64 + m * 16 + lk * 4;
        u32x2 pk;
        pk[0] = cvt_pk_bf16(acc[m][n][0] + bv, acc[m][n][1] + bv);
        pk[1] = cvt_pk_bf16(acc[m][n][2] + bv, acc[m][n][3] + bv);
        *(u32x2*)&smem[c * 128 + (r0 ^ ((c & 7) << 3))] = pk;
      }
    }
    __syncthreads();
    constexpr int TPC = 256 / BN;
    constexpr int SPT = 128 / TPC;
    const int d_ = tid / TPC, sq = tid % TPC;
    const int gcol = n0 + d_;
    const int hh = (gcol - 1024) >> 6, dd = gcol & 63;
    const int b_ = m0 >> 11, s0g = m0 & 2047;
    ushort_t* dst = VtD + (((size_t)(z * 2 + b_) * 8 + hh) * 64 + dd) * 2048 + s0g;
    #pragma unroll
    for (int it = 0; it < SPT / 8; ++it){
      const int s0 = sq * SPT + it * 8;
      bf16x8 v = *(const bf16x8*)&smem[d_ * 128 + (s0 ^ ((d_ & 7) << 3))];
      *(bf16x8*)&dst[s0] = v;
    }
    return;
  }

  if (VT && n0 >= 512){
    // K-section: pack [128 r][64 c] bf16 into LDS, then vector-scatter live rows
    #pragma unroll
    for (int n = 0; n < NB; ++n){
      const int c = wc * (BN / 2) + n * 16 + lr;
      const float bv = bias[n0 + c];
      #pragma unroll
      for (int m = 0; m < 4; ++m){
        const int r0 = wr * 64 + m * 16 + lk * 4;
        #pragma unroll
        for (int j = 0; j < 4; ++j)
          smem[(r0 + j) * 64 + c] = f2bf(acc[m][n][j] + bv);
      }
    }
    __syncthreads();
    const int b_ = m0 >> 11;
    const int sbase = m0 & 2047;
    const int* posb = pos + b_ * 2049;
    ushort_t* const KCz = KCp + (size_t)(z * 2 + b_) * 2048 * 512;
    const int col0 = n0 - 512;
    #pragma unroll
    for (int it = 0; it < 4; ++it){
      const int idx = it * 256 + tid;        // 0..1023
      const int r = idx >> 3, cc8 = idx & 7;
      const int p0 = posb[sbase + r], p1 = posb[sbase + r + 1];
      if (p1 > p0){
        const bf16x8 v = *(const bf16x8*)&smem[r * 64 + cc8 * 8];
        *(bf16x8*)&KCz[(size_t)p0 * 512 + col0 + cc8 * 8] = v;
      }
    }
    return;
  }

  void* Cz = BF16OUT ? (void*)((ushort_t*)Cv + (size_t)z * sC)
                     : (void*)((float*)Cv + (size_t)z * sC);
  gemm_store<BF16OUT, BN>(acc, bias, Cz, n0, m0, ldc);
}

// Merged dispatch 2: [0,96) Wcomb GEMM | [96,864) xl GEMM (XCD-swizzled) |
// [864,3168) Wq/Wk/Wv transposes | [3168,3186) bqkv | [3186,3188) mask scan |
// [3188,3316) bcomb. Transpose/scan work overlaps the latency-bound GEMM blocks.

__global__ __launch_bounds__(256)
void gemm_dual(const ushort_t* __restrict__ WoutT, const ushort_t* __restrict__ WoB,
               const float* __restrict__ zbias, ushort_t* __restrict__ WcombT,
               const ushort_t* __restrict__ xb, const ushort_t* __restrict__ WpT,
               const float* __restrict__ bp, ushort_t* __restrict__ xlb,
               const float* __restrict__ Wq, const float* __restrict__ Wk,
               const float* __restrict__ Wv, ushort_t* __restrict__ WqkvT,
               const float* __restrict__ bq, const float* __restrict__ bk,
               const float* __restrict__ bv, float* __restrict__ bqkv,
               const int* __restrict__ mask, ushort_t* __restrict__ monesC,
               int* __restrict__ pos,
               const float* __restrict__ bo, const float* __restrict__ Wout,
               const float* __restrict__ bout, float* __restrict__ bcomb){
  __shared__ ushort_t smem[128 * 64 + 64 * 64];
  __shared__ int lds_scan[4];
  __shared__ int lds_nl;
  const int bid = blockIdx.x, tid = threadIdx.x;

  if (bid < 864){
    f32x4 acc[4][2] = {};
    if (bid < 96){
      const int bx = bid & 7, by = (bid >> 3) & 3, z = bid >> 5;
      gemm_mainloop<64>(smem, WoutT + z * 512, WoB + (size_t)z * 262144,
                        512, 1536, 512, bx * 64, by * 128, acc);
      gemm_store<1, 64>(acc, zbias, WcombT + (size_t)z * 512, bx * 64, by * 128, 1536);
    } else {
      int b2 = bid - 96;
      b2 = (b2 & 7) * 96 + (b2 >> 3);
      const int bx = b2 % 24, by = b2 / 24;
      gemm_mainloop<64>(smem, xb, WpT, 512, 512, 512, bx * 64, by * 128, acc);
      gemm_store<1, 64>(acc, bp, xlb, bx * 64, by * 128, 1536);
    }
  } else if (bid < 3168){
    float* tile = (float*)smem;
    int idx = bid - 864;
    int w = idx / 768, r = idx % 768;
    int zz = r >> 8, t = r & 255;
    int bx = t & 15, by = t >> 4;
    if (w == 0)      do_transpose_seg(tile, Wq + zz * 262144, WqkvT + (size_t)zz * 786432, 512, 512, bx, by, CLOG2E, tid);
    else if (w == 1) do_transpose_seg(tile, Wk + zz * 262144, WqkvT + 262144 + (size_t)zz * 786432, 512, 512, bx, by, 1.0f, tid);
    else             do_transpose_seg(tile, Wv + zz * 262144, WqkvT + 524288 + (size_t)zz * 786432, 512, 512, bx, by, 1.0f, tid);
  } else if (bid < 3186){
    int i = (bid - 3168) * 256 + tid;
    if (i < 4608){
      int l = i / 1536, j = i % 1536;
      float v = (j < 512) ? bq[l * 512 + j] * CLOG2E
              : (j < 1024 ? bk[l * 512 + j - 512] : bv[l * 512 + j - 1024]);
      bqkv[i] = v;
    }
  } else if (bid < 3188){
    // mask scan: one block per batch b
    const int b = bid - 3186;
    int v[8]; int s8 = 0;
    #pragma unroll
    for (int i = 0; i < 8; ++i){ v[i] = mask[b * 2048 + tid * 8 + i] ? 1 : 0; s8 += v[i]; }
    const int lane = tid & 63, wid2 = tid >> 6;
    int ws = s8;
    #pragma unroll
    for (int off = 1; off < 64; off <<= 1){
      int t = __shfl_up(ws, off);
      if (lane >= off) ws += t;
    }
    if (lane == 63) lds_scan[wid2] = ws;
    __syncthreads();
    int woff = 0;
    for (int w = 0; w < wid2; ++w) woff += lds_scan[w];
    int run = woff + ws - s8;
    #pragma unroll
    for (int i = 0; i < 8; ++i){ pos[b * 2049 + tid * 8 + i] = run; run += v[i]; }
    if (tid == 255){ pos[b * 2049 + 2048] = run; lds_nl = run; }
    __syncthreads();
    const int nl = lds_nl;
    #pragma unroll
    for (int i = 0; i < 8; ++i){
      int j = tid * 8 + i;
      monesC[b * 2048 + j] = (j < nl) ? (ushort_t)0x3F80 : (ushort_t)0;
    }
  } else {
    int wid = tid >> 6, lane = tid & 63;
    int n = (bid - 3188) * 4 + wid;
    float s = 0.f;
    #pragma unroll
    for (int it = 0; it < 24; ++it){
      int k = it * 64 + lane;
      s += bo[k] * Wout[(size_t)k * 512 + n];
    }
    #pragma unroll
    for (int off = 32; off; off >>= 1) s += __shfl_xor(s, off);
    if (lane == 0) bcomb[n] = s + bout[n];
  }
}

// ---------------- LayerNorm (bf16 input) ----------------

__global__ __launch_bounds__(256)
void ln_kernel(const ushort_t* __restrict__ xlb, ushort_t* __restrict__ xn,
               const float* __restrict__ gamma, const float* __restrict__ beta){
  int rid = blockIdx.x * 4 + (threadIdx.x >> 6);
  int lane = threadIdx.x & 63;
  int l = rid >> 12, bs = rid & 4095;
  const ushort_t* row = xlb + (size_t)bs * 1536 + l * 512;
  ushort_t* orow = xn + (size_t)bs * 1536 + l * 512;
  const bf16x8 a = *(const bf16x8*)(row + lane * 8);
  float vals[8];
  #pragma unroll
  for (int j = 0; j < 8; ++j) vals[j] = bf2f((ushort_t)a[j]);
  float s = 0.f, ss = 0.f;
  #pragma unroll
  for (int j = 0; j < 8; ++j){ s += vals[j]; ss += vals[j] * vals[j]; }
  #pragma unroll
  for (int off = 32; off; off >>= 1){
    s += __shfl_xor(s, off);
    ss += __shfl_xor(ss, off);
  }
  float mean = s * (1.0f / 512.0f);
  float var = ss * (1.0f / 512.0f) - mean * mean;
  float inv = rsqrtf(var + 1e-5f);
  const float* g = gamma + l * 512 + lane * 8;
  const float* be = beta + l * 512 + lane * 8;
  float4 g0 = ((const float4*)g)[0], g1 = ((const float4*)g)[1];
  float4 be0 = ((const float4*)be)[0], be1 = ((const float4*)be)[1];
  float gs[8] = {g0.x, g0.y, g0.z, g0.w, g1.x, g1.y, g1.z, g1.w};
  float bs8[8] = {be0.x, be0.y, be0.z, be0.w, be1.x, be1.y, be1.z, be1.w};
  bf16x8 r;
  #pragma unroll
  for (int j = 0; j < 8; ++j)
    r[j] = (short)f2bf((vals[j] - mean) * inv * gs[j] + bs8[j]);
  *(bf16x8*)(orow + lane * 8) = r;
}

// ---------------- Flash attention over COMPACTED keys ----------------
// Q from dense QbD [3][4096][512] (stride 512).

__global__ __launch_bounds__(256)
void attn_kernel(const ushort_t* __restrict__ QbD, const ushort_t* __restrict__ KC,
                 const ushort_t* __restrict__ VtC, const ushort_t* __restrict__ mones,
                 const int* __restrict__ pos, ushort_t* __restrict__ att){
  const int hz = blockIdx.x, qb = blockIdx.y;
  const int h = hz & 7, z = hz >> 3;
  const int l = z >> 1, b = z & 1;
  const ushort_t* Qb = QbD + ((size_t)l * 4096 + b * 2048) * 512 + h * 64;
  const ushort_t* Kb = KC + (size_t)z * 2048 * 512 + h * 64;      // [pad nlive][512]
  const ushort_t* Vt = VtC + ((size_t)(z * 8 + h) * 64) * 2048;   // [64 d][2048 k]

  const int nl = pos[b * 2049 + 2048];
  const int nt2 = (((nl + 63) >> 6) + 1) & ~1;

  __shared__ __attribute__((aligned(16))) ushort_t Ks[2][64 * 64];
  __shared__ __attribute__((aligned(16))) ushort_t Vs[2][64 * 64];

  const int tid = threadIdx.x, wid = tid >> 6, lane = tid & 63;
  const int lr = lane & 15, lk = lane >> 4;
  const int sw = lr & 7;
  const int qrow = qb * 64 + wid * 16 + lr;

  const ushort_t* qp = Qb + (size_t)qrow * 512 + lk * 8;
  const bf16x8 q0 = *(const bf16x8*)qp;
  const bf16x8 q1 = *(const bf16x8*)(qp + 32);

  const int ch0 = wid * 64 + lane, ch1 = 256 + wid * 64 + lane;
  const int r0_ = ch0 >> 3, c0_ = (ch0 & 7) ^ (r0_ & 7);
  const int r1_ = ch1 >> 3, c1_ = (ch1 & 7) ^ (r1_ & 7);
  const ushort_t* kg0 = Kb + (size_t)r0_ * 512 + c0_ * 8;
  const ushort_t* kg1 = Kb + (size_t)r1_ * 512 + c1_ * 8;
  const ushort_t* vg0 = Vt + (size_t)r0_ * 2048 + c0_ * 8;
  const ushort_t* vg1 = Vt + (size_t)r1_ * 2048 + c1_ * 8;
  ushort_t* const kdA0 = &Ks[0][(wid * 64) * 8];
  ushort_t* const kdA1 = &Ks[0][(256 + wid * 64) * 8];
  ushort_t* const kdB0 = &Ks[1][(wid * 64) * 8];
  ushort_t* const kdB1 = &Ks[1][(256 + wid * 64) * 8];
  ushort_t* const vdA0 = &Vs[0][(wid * 64) * 8];
  ushort_t* const vdA1 = &Vs[0][(256 + wid * 64) * 8];
  ushort_t* const vdB0 = &Vs[1][(wid * 64) * 8];
  ushort_t* const vdB1 = &Vs[1][(256 + wid * 64) * 8];

  const ushort_t* const kbA0 = &Ks[0][lr * 64 + (lk ^ sw) * 8];
  const ushort_t* const kbA4 = &Ks[0][lr * 64 + ((lk ^ sw) ^ 4) * 8];
  const ushort_t* const kbB0 = &Ks[1][lr * 64 + (lk ^ sw) * 8];
  const ushort_t* const kbB4 = &Ks[1][lr * 64 + ((lk ^ sw) ^ 4) * 8];
  const ushort_t* const vbA0 = &Vs[0][lr * 64 + (lk ^ sw) * 8];
  const ushort_t* const vbA4 = &Vs[0][lr * 64 + ((lk ^ sw) ^ 4) * 8];
  const ushort_t* const vbB0 = &Vs[1][lr * 64 + (lk ^ sw) * 8];
  const ushort_t* const vbB4 = &Vs[1][lr * 64 + ((lk ^ sw) ^ 4) * 8];

  const ushort_t* pm = mones + b * 2048 + lk * 8;

  f32x4 o[4] = {};
  f32x4 lrun = {0.f, 0.f, 0.f, 0.f};

  gload_lds16(kg0, kdA0); gload_lds16(kg1, kdA1);
  gload_lds16(vg0, vdA0); gload_lds16(vg1, vdA1);
  kg0 += 32768; kg1 += 32768; vg0 += 64; vg1 += 64;
  __syncthreads();

  auto tile_step = [&](const ushort_t* kb0, const ushort_t* kb4,
                       const ushort_t* vb0, const ushort_t* vb4,
                       ushort_t* sk0, ushort_t* sk1, ushort_t* sv0, ushort_t* sv1,
                       bool doStage){
    if (doStage){
      gload_lds16(kg0, sk0); gload_lds16(kg1, sk1);
      gload_lds16(vg0, sv0); gload_lds16(vg1, sv1);
      kg0 += 32768; kg1 += 32768; vg0 += 64; vg1 += 64;
    }
    const bf16x8 mo0 = *(const bf16x8*)pm;
    const bf16x8 mo1 = *(const bf16x8*)(pm + 32);
    pm += 64;

    f32x4 t[4];
    __builtin_amdgcn_s_setprio(1);
    #pragma unroll
    for (int hh = 0; hh < 4; ++hh){
      const bf16x8 kf0 = *(const bf16x8*)(kb0 + hh * 1024);
      const bf16x8 kf1 = *(const bf16x8*)(kb4 + hh * 1024);
      f32x4 tt = {0.f, 0.f, 0.f, 0.f};
      tt = __builtin_amdgcn_mfma_f32_16x16x32_bf16(kf0, q0, tt, 0, 0, 0);
      tt = __builtin_amdgcn_mfma_f32_16x16x32_bf16(kf1, q1, tt, 0, 0, 0);
      t[hh] = tt;
    }
    __builtin_amdgcn_s_setprio(0);

    unsigned a00, a01, a10, a11, a20, a21, a30, a31;
    a00 = cvt_pk_bf16(exp2_fast(t[0][0]), exp2_fast(t[0][1]));
    a01 = cvt_pk_bf16(exp2_fast(t[0][2]), exp2_fast(t[0][3]));
    a10 = cvt_pk_bf16(exp2_fast(t[1][0]), exp2_fast(t[1][1]));
    a11 = cvt_pk_bf16(exp2_fast(t[1][2]), exp2_fast(t[1][3]));
    a20 = cvt_pk_bf16(exp2_fast(t[2][0]), exp2_fast(t[2][1]));
    a21 = cvt_pk_bf16(exp2_fast(t[2][2]), exp2_fast(t[2][3]));
    a30 = cvt_pk_bf16(exp2_fast(t[3][0]), exp2_fast(t[3][1]));
    a31 = cvt_pk_bf16(exp2_fast(t[3][2]), exp2_fast(t[3][3]));
    asm("v_permlane32_swap_b32 %0, %1" : "+v"(a00), "+v"(a10));
    asm("v_permlane32_swap_b32 %0, %1" : "+v"(a01), "+v"(a11));
    asm("v_permlane32_swap_b32 %0, %1" : "+v"(a20), "+v"(a30));
    asm("v_permlane32_swap_b32 %0, %1" : "+v"(a21), "+v"(a31));
    asm("v_permlane16_swap_b32 %0, %1" : "+v"(a00), "+v"(a10));
    asm("v_permlane16_swap_b32 %0, %1" : "+v"(a01), "+v"(a11));
    asm("v_permlane16_swap_b32 %0, %1" : "+v"(a20), "+v"(a30));
    asm("v_permlane16_swap_b32 %0, %1" : "+v"(a21), "+v"(a31));
    const u32x4 f0 = {a00, a01, a10, a11};
    const u32x4 f1 = {a20, a21, a30, a31};
    const bf16x8 pf0 = __builtin_bit_cast(bf16x8, f0);
    const bf16x8 pf1 = __builtin_bit_cast(bf16x8, f1);

    __builtin_amdgcn_s_setprio(1);
    lrun = __builtin_amdgcn_mfma_f32_16x16x32_bf16(pf0, mo0, lrun, 0, 0, 0);
    lrun = __builtin_amdgcn_mfma_f32_16x16x32_bf16(pf1, mo1, lrun, 0, 0, 0);
    #pragma unroll
    for (int n = 0; n < 4; ++n){
      const bf16x8 v0 = *(const bf16x8*)(vb0 + n * 1024);
      const bf16x8 v1 = *(const bf16x8*)(vb4 + n * 1024);
      o[n] = __builtin_amdgcn_mfma_f32_16x16x32_bf16(pf0, v0, o[n], 0, 0, 0);
      o[n] = __builtin_amdgcn_mfma_f32_16x16x32_bf16(pf1, v1, o[n], 0, 0, 0);
    }
    __builtin_amdgcn_s_setprio(0);
    __syncthreads();
  };

  for (int kt2 = 0; kt2 < nt2; kt2 += 2){
    tile_step(kbA0, kbA4, vbA0, vbA4, kdB0, kdB1, vdB0, vdB1, true);
    tile_step(kbB0, kbB4, vbB0, vbB4, kdA0, kdA1, vdA0, vdA1, kt2 + 2 < nt2);
  }

  float invj[4];
  #pragma unroll
  for (int j = 0; j < 4; ++j) invj[j] = 1.0f / lrun[j];
  const size_t arow0 = (size_t)(b * 2048 + qb * 64 + wid * 16);
  #pragma unroll
  for (int n = 0; n < 4; ++n)
    #pragma unroll
    for (int j = 0; j < 4; ++j)
      att[(arow0 + lk * 4 + j) * 1536 + l * 512 + h * 64 + n * 16 + lr] = f2bf(o[n][j] * invj[j]);
}

// ---------------- launch ----------------

extern "C" void kernel_launch(void* const* d_in, const int* in_sizes, int n_in,
                              void* d_out, int out_size, void* d_ws, size_t ws_size,
                              hipStream_t stream){
  const float* x    = (const float*)d_in[0];
  const int*   mask = (const int*)d_in[1];
  const float* Wp   = (const float*)d_in[2];
  const float* bp   = (const float*)d_in[3];
  const float* gamma= (const float*)d_in[4];
  const float* beta = (const float*)d_in[5];
  const float* Wq   = (const float*)d_in[6];
  const float* bq   = (const float*)d_in[7];
  const float* Wk   = (const float*)d_in[8];
  const float* bk   = (const float*)d_in[9];
  const float* Wv   = (const float*)d_in[10];
  const float* bv   = (const float*)d_in[11];
  const float* Wo   = (const float*)d_in[12];
  const float* bo   = (const float*)d_in[13];
  const float* Wout = (const float*)d_in[14];
  const float* bout = (const float*)d_in[15];

  char* ws = (char*)d_ws;
  size_t off = 0;
  auto alloc = [&](size_t bytes){ void* p = ws + off; off += (bytes + 255) & ~(size_t)255; return p; };
  ushort_t* xb    = (ushort_t*)alloc(4096ull * 512 * 2);
  ushort_t* WpT   = (ushort_t*)alloc(1536ull * 512 * 2);
  ushort_t* WqkvT = (ushort_t*)alloc(3ull * 1536 * 512 * 2);
  ushort_t* WoB   = (ushort_t*)alloc(3ull * 512 * 512 * 2);
  ushort_t* WoutT = (ushort_t*)alloc(512ull * 1536 * 2);
  ushort_t* WcombT= (ushort_t*)alloc(512ull * 1536 * 2);
  float*    bqkv  = (float*)alloc(3ull * 1536 * 4);
  float*    zbias = (float*)alloc(512ull * 4);
  float*    bcomb = (float*)alloc(512ull * 4);
  ushort_t* monesC= (ushort_t*)alloc(4096ull * 2);
  int*      pos   = (int*)alloc(2ull * 2049 * 4);
  char*     xlbuf = (char*)alloc(4096ull * 1536 * 4);          // 25.17 MB scratch
  ushort_t* xn    = (ushort_t*)alloc(4096ull * 1536 * 2);
  ushort_t* QbD   = (ushort_t*)alloc(3ull * 4096 * 512 * 2);   // dense Q
  ushort_t* VtD   = (ushort_t*)alloc(6ull * 512 * 2048 * 2);   // dense V^T
  ushort_t* KC    = (ushort_t*)alloc(6ull * 2048 * 512 * 2);   // compacted K
  // xlbuf: xlb (bf16, 12.58 MB) lives until ln; then att + VtC reuse the region.
  ushort_t* xlb   = (ushort_t*)xlbuf;
  ushort_t* att   = (ushort_t*)xlbuf;
  ushort_t* VtC   = (ushort_t*)(xlbuf + 12582912);

  // dispatch 1: prep-A (4354 blocks) — only gemm_dual's inputs
  prep_kernel<<<4354, 256, 0, stream>>>(x, Wo, Wp, Wout,
                                        xb, WoB, WpT, WoutT, zbias);

  // dispatch 2: Wcomb GEMM + xl GEMM + Wq/Wk/Wv transposes + bqkv + scan + bcomb
  gemm_dual<<<3316, 256, 0, stream>>>(WoutT, WoB, zbias, WcombT, xb, WpT, bp, xlb,
                                      Wq, Wk, Wv, WqkvT, bq, bk, bv, bqkv,
                                      mask, monesC, pos, bo, Wout, bout, bcomb);

  // LayerNorm (bf16 in) -> xn bf16
  ln_kernel<<<3072, 256, 0, stream>>>(xlb, xn, gamma, beta);
  // qkv GEMM; Q -> QbD (dense), K vector-scattered compacted -> KC, V -> VtD
  gemm_bt<1, 64, 1><<<dim3(24, 32, 3), 256, 0, stream>>>(xn, WqkvT, bqkv, QbD,
      4096, 1536, 512, 1536, 512, 512, 512, 786432, 4096ll * 512, 1536,
      VtD, KC, pos);
  // V-gather live cols -> VtC; zero K/V pads (774 blocks)
  compact_kernel<<<dim3(129, 6), 256, 0, stream>>>(VtD, pos, KC, VtC);
  // flash attention over compacted keys
  attn_kernel<<<dim3(48, 32, 1), 256, 0, stream>>>(QbD, KC, VtC, monesC, pos, att);
  // out = att @ Wcomb_stack + bcomb   fp32 [4096][512]
  gemm_bt<0, 32, 0><<<dim3(16, 32, 1), 256, 0, stream>>>(att, WcombT, bcomb, (float*)d_out,
      4096, 512, 1536, 1536, 1536, 512, 0, 0, 0, 0, nullptr, nullptr, nullptr);
}

// Round 23
// 156.292 us; speedup vs baseline: 1.0890x; 1.0207x over previous
//
#include <hip/hip_runtime.h>

typedef unsigned short ushort_t;
typedef __attribute__((ext_vector_type(8))) short bf16x8;
typedef __attribute__((ext_vector_type(4))) float f32x4;
typedef __attribute__((ext_vector_type(4))) unsigned int u32x4;
typedef __attribute__((ext_vector_type(2))) unsigned int u32x2;

#define DI static __device__ __forceinline__

DI ushort_t f2bf(float f){
  unsigned u = __builtin_bit_cast(unsigned, f);
  u += 0x7fffu + ((u >> 16) & 1u);
  return (ushort_t)(u >> 16);
}
DI float bf2f(ushort_t h){ unsigned u = ((unsigned)h) << 16; return __builtin_bit_cast(float, u); }

DI unsigned cvt_pk_bf16(float a, float b){
  unsigned r;
  asm("v_cvt_pk_bf16_f32 %0, %1, %2" : "=v"(r) : "v"(a), "v"(b));
  return r;
}

// raw v_exp_f32 (exp2) — skips libm's subnormal/range guard
DI float exp2_fast(float x){
  float r;
  asm("v_exp_f32 %0, %1" : "=v"(r) : "v"(x));
  return r;
}

DI void gload_lds16(const void* g, void* l){
  __builtin_amdgcn_global_load_lds((const __attribute__((address_space(1))) void*)g,
                                   (__attribute__((address_space(3))) void*)l, 16, 0, 0);
}

// 0.125 * log2(e): folded into Wq/bq so QK^T output is in the exp2 domain
#define CLOG2E 0.18033688011112042f

// shared helpers ------------------------------------------------------------

DI void do_cast_seg(const float* __restrict__ in, ushort_t* __restrict__ out,
                    int i, int n4){
  if (i >= n4) return;
  float4 v = ((const float4*)in)[i];
  ushort_t r0 = f2bf(v.x), r1 = f2bf(v.y), r2 = f2bf(v.z), r3 = f2bf(v.w);
  ushort_t* o = out + (size_t)i * 4;
  o[0] = r0; o[1] = r1; o[2] = r2; o[3] = r3;
}

DI void do_transpose_seg(float* __restrict__ tile,  // [32][33] floats
                         const float* __restrict__ src, ushort_t* __restrict__ dst,
                         int R, int C, int bx, int by, float scale, int tid){
  int c0 = bx * 32, r0 = by * 32;
  int tx = tid & 31, ty = tid >> 5;
  #pragma unroll
  for (int p = 0; p < 4; ++p)
    tile[(ty + p * 8) * 33 + tx] = src[(size_t)(r0 + ty + p * 8) * C + c0 + tx];
  __syncthreads();
  #pragma unroll
  for (int p = 0; p < 4; ++p){
    int rr = ty + p * 8;
    dst[(size_t)(c0 + rr) * R + r0 + tx] = f2bf(tile[tx * 33 + rr] * scale);
  }
}

// ---------------- prep-A: only what gemm_dual needs ----------------
// [0,2048) cast x | [2048,2816) cast Wo | [2816,3584) transpose Wp
// [3584,4352) transpose Wout | [4352,4354) zbias

__global__ __launch_bounds__(256)
void prep_kernel(const float* __restrict__ x, const float* __restrict__ Wo,
                 const float* __restrict__ Wp, const float* __restrict__ Wout,
                 ushort_t* __restrict__ xb, ushort_t* __restrict__ WoB,
                 ushort_t* __restrict__ WpT, ushort_t* __restrict__ WoutT,
                 float* __restrict__ zbias){
  __shared__ float tile[32 * 33];
  const int bid = blockIdx.x, tid = threadIdx.x;
  if (bid < 2048){
    do_cast_seg(x, xb, bid * 256 + tid, 524288);
  } else if (bid < 2816){
    do_cast_seg(Wo, WoB, (bid - 2048) * 256 + tid, 196608);
  } else if (bid < 3584){
    int r = bid - 2816;
    int zz = r >> 8, t = r & 255;
    do_transpose_seg(tile, Wp + zz * 262144, WpT + zz * 262144, 512, 512,
                     t & 15, t >> 4, 1.0f, tid);
  } else if (bid < 4352){
    int t = bid - 3584;
    do_transpose_seg(tile, Wout, WoutT, 1536, 512, t & 15, t >> 4, 1.0f, tid);
  } else {
    int i = (bid - 4352) * 256 + tid;
    if (i < 512) zbias[i] = 0.f;
  }
}

// ---------------- compaction (after qkv GEMM): V-gather + pad zeroing ----------------

__global__ __launch_bounds__(256)
void compact_kernel(const ushort_t* __restrict__ VtD, const int* __restrict__ pos,
                    ushort_t* __restrict__ KC, ushort_t* __restrict__ VtC){
  const int zb = blockIdx.y, b = zb & 1;
  const int tid = threadIdx.x;
  const int xb_ = blockIdx.x;
  if (xb_ < 128){
    const int g = xb_;                     // 0..127 -> 4 d-rows each
    const int nl = pos[b * 2049 + 2048];
    const int nt2e = ((((nl + 63) >> 6) + 1) & ~1) * 64;
    int pp[9];
    #pragma unroll
    for (int j = 0; j < 9; ++j) pp[j] = pos[b * 2049 + tid * 8 + j];
    const size_t rbase = (size_t)zb * 512 + g * 4;
    #pragma unroll
    for (int rr = 0; rr < 4; ++rr){
      const ushort_t* src = VtD + (rbase + rr) * 2048 + tid * 8;
      ushort_t* dstrow = VtC + (rbase + rr) * 2048;
      bf16x8 v = *(const bf16x8*)src;
      #pragma unroll
      for (int j = 0; j < 8; ++j)
        if (pp[j + 1] > pp[j]) dstrow[pp[j]] = (ushort_t)v[j];
      for (int ccol = nl + tid; ccol < nt2e; ccol += 256) dstrow[ccol] = 0;
    }
  } else {
    const int nl = pos[b * 2049 + 2048];
    const int nt2e = ((((nl + 63) >> 6) + 1) & ~1) * 64;
    const int padShorts = (nt2e - nl) * 512;
    bf16x8 zz = {};
    for (int j = tid * 8; j < padShorts; j += 2048)
      *(bf16x8*)(KC + ((size_t)zb * 2048 + nl) * 512 + j) = zz;
  }
}

// ---------------- GEMM core: double-buffered 2-phase, BK=32 ----------------
// LDS = 2 x (128 + BN) x 32 bf16  (24 KB at BN=64 -> occupancy preserved).
// Per iter: issue stage(t+1) -> ds_read + 8*NB/2 MFMA on buf t -> one barrier.

template<int BN>
DI void gemm_mainloop(ushort_t* __restrict__ smem,
                      const ushort_t* __restrict__ A, const ushort_t* __restrict__ Bt,
                      int K, int lda, int ldb, int n0, int m0,
                      f32x4 (&acc)[4][BN / 32]){
  constexpr int NB = BN / 32;
  ushort_t* const As0 = smem;                  // [2][128*32]
  ushort_t* const Bs0 = smem + 2 * 128 * 32;   // [2][BN*32]
  const int tid = threadIdx.x, wid = tid >> 6, lane = tid & 63;
  const int wr = wid >> 1, wc = wid & 1, lr = lane & 15, lk = lane >> 4;

  // A: 512 chunks of 16B -> 2 per thread; B: BN*4 chunks.
  auto stage = [&](int buf, int k0){
    ushort_t* const Ad = As0 + buf * (128 * 32);
    ushort_t* const Bd = Bs0 + buf * (BN * 32);
    #pragma unroll
    for (int i = 0; i < 2; ++i){
      const int ch = i * 256 + tid;
      const int row = ch >> 2, cc = ch & 3;
      gload_lds16(A + (size_t)(m0 + row) * lda + (k0 + cc * 8),
                  Ad + (i * 256 + wid * 64) * 8);
    }
    if (BN == 64){
      const int ch = tid;                      // 256 chunks
      const int row = ch >> 2, cc = ch & 3;
      gload_lds16(Bt + (size_t)(n0 + row) * ldb + (k0 + cc * 8),
                  Bd + (wid * 64) * 8);
    } else {                                   // BN==32: 128 chunks, 2x duplicated
      const int ch = (wid & 1) * 64 + lane;
      const int row = ch >> 2, cc = ch & 3;
      gload_lds16(Bt + (size_t)(n0 + row) * ldb + (k0 + cc * 8),
                  Bd + ((wid & 1) * 64) * 8);
    }
  };

  stage(0, 0);
  __syncthreads();

  const int nk = K >> 5;
  for (int t = 0; t < nk; ++t){
    const int cur = t & 1;
    if (t + 1 < nk) stage(cur ^ 1, (t + 1) * 32);

    const ushort_t* const Ac = As0 + cur * (128 * 32);
    const ushort_t* const Bc = Bs0 + cur * (BN * 32);
    bf16x8 af[4], bfr[NB];
    #pragma unroll
    for (int m = 0; m < 4; ++m)
      af[m] = *(const bf16x8*)&Ac[(wr * 64 + m * 16 + lr) * 32 + lk * 8];
    #pragma unroll
    for (int n = 0; n < NB; ++n)
      bfr[n] = *(const bf16x8*)&Bc[(wc * (BN / 2) + n * 16 + lr) * 32 + lk * 8];
    #pragma unroll
    for (int m = 0; m < 4; ++m)
      #pragma unroll
      for (int n = 0; n < NB; ++n)
        acc[m][n] = __builtin_amdgcn_mfma_f32_16x16x32_bf16(af[m], bfr[n], acc[m][n], 0, 0, 0);

    __syncthreads();   // drains stage(t+1) loads (issued before compute) + buf reuse
  }
}

template<int BF16OUT, int BN>
DI void gemm_store(const f32x4 (&acc)[4][BN / 32], const float* __restrict__ bias,
                   void* __restrict__ Cv, int n0, int m0, int ldc){
  constexpr int NB = BN / 32;
  const int tid = threadIdx.x, wid = tid >> 6, lane = tid & 63;
  const int wr = wid >> 1, wc = wid & 1, lr = lane & 15, lk = lane >> 4;
  #pragma unroll
  for (int n = 0; n < NB; ++n){
    const int col = n0 + wc * (BN / 2) + n * 16 + lr;
    const float bv = bias[col];
    #pragma unroll
    for (int m = 0; m < 4; ++m){
      const int row0 = m0 + wr * 64 + m * 16 + lk * 4;
      #pragma unroll
      for (int j = 0; j < 4; ++j){
        const float v = acc[m][n][j] + bv;
        const size_t idx = (size_t)(row0 + j) * ldc + col;
        if (BF16OUT) ((ushort_t*)Cv)[idx] = f2bf(v);
        else         ((float*)Cv)[idx] = v;
      }
    }
  }
}

// ---------------- GEMM globals (XCD-colocated via bijective remap) ----------------
// VT=1 (qkv GEMM): Q-section -> dense QbD (ldc=512); K-section rows packed via
// LDS bounce then VECTOR-scattered to compacted KC; V-section transposed to VtD.

template<int BF16OUT, int BN, int VT>
__global__ __launch_bounds__(256)
void gemm_bt(const ushort_t* __restrict__ A, const ushort_t* __restrict__ Bt,
             const float* __restrict__ bias, void* __restrict__ Cv,
             int M, int N, int K, int lda, int ldb, int ldc,
             long long sA, long long sB, long long sC, long long sBias,
             ushort_t* __restrict__ VtD, ushort_t* __restrict__ KCp,
             const int* __restrict__ pos){
  constexpr int NB = BN / 32;
  __shared__ ushort_t smem[2 * (128 + BN) * 32];
  const int gx = gridDim.x, gy = gridDim.y;
  const int nwg = gx * gy * gridDim.z;
  int flat = blockIdx.x + gx * (blockIdx.y + gy * blockIdx.z);
  flat = (flat & 7) * (nwg >> 3) + (flat >> 3);
  const int bxi = flat % gx;
  const int byi = (flat / gx) % gy;
  const int z   = flat / (gx * gy);

  A += (size_t)z * sA; Bt += (size_t)z * sB; bias += (size_t)z * sBias;
  const int n0 = bxi * BN, m0 = byi * 128;
  const int tid = threadIdx.x, wid = tid >> 6, lane = tid & 63;
  const int wr = wid >> 1, wc = wid & 1, lr = lane & 15, lk = lane >> 4;

  f32x4 acc[4][NB] = {};
  gemm_mainloop<BN>(smem, A, Bt, K, lda, ldb, n0, m0, acc);

  if (VT && n0 >= 1024){
    // V-section: transposed dense write to VtD via swizzled LDS bounce
    #pragma unroll
    for (int n = 0; n < NB; ++n){
      const int c = wc * (BN / 2) + n * 16 + lr;
      const float bv = bias[n0 + c];
      #pragma unroll
      for (int m = 0; m < 4; ++m){
        const int r0 = wr * 64 + m * 16 + lk * 4;
        u32x2 pk;
        pk[0] = cvt_pk_bf16(acc[m][n][0] + bv, acc[m][n][1] + bv);
        pk[1] = cvt_pk_bf16(acc[m][n][2] + bv, acc[m][n][3] + bv);
        *(u32x2*)&smem[c * 128 + (r0 ^ ((c & 7) << 3))] = pk;
      }
    }
    __syncthreads();
    constexpr int TPC = 256 / BN;
    constexpr int SPT = 128 / TPC;
    const int d_ = tid / TPC, sq = tid % TPC;
    const int gcol = n0 + d_;
    const int hh = (gcol - 1024) >> 6, dd = gcol & 63;
    const int b_ = m0 >> 11, s0g = m0 & 2047;
    ushort_t* dst = VtD + (((size_t)(z * 2 + b_) * 8 + hh) * 64 + dd) * 2048 + s0g;
    #pragma unroll
    for (int it = 0; it < SPT / 8; ++it){
      const int s0 = sq * SPT + it * 8;
      bf16x8 v = *(const bf16x8*)&smem[d_ * 128 + (s0 ^ ((d_ & 7) << 3))];
      *(bf16x8*)&dst[s0] = v;
    }
    return;
  }

  if (VT && n0 >= 512){
    // K-section: pack [128 r][64 c] bf16 into LDS, then vector-scatter live rows
    #pragma unroll
    for (int n = 0; n < NB; ++n){
      const int c = wc * (BN / 2) + n * 16 + lr;
      const float bv = bias[n0 + c];
      #pragma unroll
      for (int m = 0; m < 4; ++m){
        const int r0 = wr * 64 + m * 16 + lk * 4;
        #pragma unroll
        for (int j = 0; j < 4; ++j)
          smem[(r0 + j) * 64 + c] = f2bf(acc[m][n][j] + bv);
      }
    }
    __syncthreads();
    const int b_ = m0 >> 11;
    const int sbase = m0 & 2047;
    const int* posb = pos + b_ * 2049;
    ushort_t* const KCz = KCp + (size_t)(z * 2 + b_) * 2048 * 512;
    const int col0 = n0 - 512;
    #pragma unroll
    for (int it = 0; it < 4; ++it){
      const int idx = it * 256 + tid;        // 0..1023
      const int r = idx >> 3, cc8 = idx & 7;
      const int p0 = posb[sbase + r], p1 = posb[sbase + r + 1];
      if (p1 > p0){
        const bf16x8 v = *(const bf16x8*)&smem[r * 64 + cc8 * 8];
        *(bf16x8*)&KCz[(size_t)p0 * 512 + col0 + cc8 * 8] = v;
      }
    }
    return;
  }

  void* Cz = BF16OUT ? (void*)((ushort_t*)Cv + (size_t)z * sC)
                     : (void*)((float*)Cv + (size_t)z * sC);
  gemm_store<BF16OUT, BN>(acc, bias, Cz, n0, m0, ldc);
}

// Merged dispatch 2: [0,96) Wcomb GEMM | [96,864) xl GEMM (XCD-swizzled) |
// [864,3168) Wq/Wk/Wv transposes | [3168,3186) bqkv | [3186,3188) mask scan |
// [3188,3316) bcomb.

__global__ __launch_bounds__(256)
void gemm_dual(const ushort_t* __restrict__ WoutT, const ushort_t* __restrict__ WoB,
               const float* __restrict__ zbias, ushort_t* __restrict__ WcombT,
               const ushort_t* __restrict__ xb, const ushort_t* __restrict__ WpT,
               const float* __restrict__ bp, ushort_t* __restrict__ xlb,
               const float* __restrict__ Wq, const float* __restrict__ Wk,
               const float* __restrict__ Wv, ushort_t* __restrict__ WqkvT,
               const float* __restrict__ bq, const float* __restrict__ bk,
               const float* __restrict__ bv, float* __restrict__ bqkv,
               const int* __restrict__ mask, ushort_t* __restrict__ monesC,
               int* __restrict__ pos,
               const float* __restrict__ bo, const float* __restrict__ Wout,
               const float* __restrict__ bout, float* __restrict__ bcomb){
  __shared__ ushort_t smem[2 * (128 + 64) * 32];
  __shared__ int lds_scan[4];
  __shared__ int lds_nl;
  const int bid = blockIdx.x, tid = threadIdx.x;

  if (bid < 864){
    f32x4 acc[4][2] = {};
    if (bid < 96){
      const int bx = bid & 7, by = (bid >> 3) & 3, z = bid >> 5;
      gemm_mainloop<64>(smem, WoutT + z * 512, WoB + (size_t)z * 262144,
                        512, 1536, 512, bx * 64, by * 128, acc);
      gemm_store<1, 64>(acc, zbias, WcombT + (size_t)z * 512, bx * 64, by * 128, 1536);
    } else {
      int b2 = bid - 96;
      b2 = (b2 & 7) * 96 + (b2 >> 3);
      const int bx = b2 % 24, by = b2 / 24;
      gemm_mainloop<64>(smem, xb, WpT, 512, 512, 512, bx * 64, by * 128, acc);
      gemm_store<1, 64>(acc, bp, xlb, bx * 64, by * 128, 1536);
    }
  } else if (bid < 3168){
    float* tile = (float*)smem;
    int idx = bid - 864;
    int w = idx / 768, r = idx % 768;
    int zz = r >> 8, t = r & 255;
    int bx = t & 15, by = t >> 4;
    if (w == 0)      do_transpose_seg(tile, Wq + zz * 262144, WqkvT + (size_t)zz * 786432, 512, 512, bx, by, CLOG2E, tid);
    else if (w == 1) do_transpose_seg(tile, Wk + zz * 262144, WqkvT + 262144 + (size_t)zz * 786432, 512, 512, bx, by, 1.0f, tid);
    else             do_transpose_seg(tile, Wv + zz * 262144, WqkvT + 524288 + (size_t)zz * 786432, 512, 512, bx, by, 1.0f, tid);
  } else if (bid < 3186){
    int i = (bid - 3168) * 256 + tid;
    if (i < 4608){
      int l = i / 1536, j = i % 1536;
      float v = (j < 512) ? bq[l * 512 + j] * CLOG2E
              : (j < 1024 ? bk[l * 512 + j - 512] : bv[l * 512 + j - 1024]);
      bqkv[i] = v;
    }
  } else if (bid < 3188){
    // mask scan: one block per batch b
    const int b = bid - 3186;
    int v[8]; int s8 = 0;
    #pragma unroll
    for (int i = 0; i < 8; ++i){ v[i] = mask[b * 2048 + tid * 8 + i] ? 1 : 0; s8 += v[i]; }
    const int lane = tid & 63, wid2 = tid >> 6;
    int ws = s8;
    #pragma unroll
    for (int off = 1; off < 64; off <<= 1){
      int t = __shfl_up(ws, off);
      if (lane >= off) ws += t;
    }
    if (lane == 63) lds_scan[wid2] = ws;
    __syncthreads();
    int woff = 0;
    for (int w = 0; w < wid2; ++w) woff += lds_scan[w];
    int run = woff + ws - s8;
    #pragma unroll
    for (int i = 0; i < 8; ++i){ pos[b * 2049 + tid * 8 + i] = run; run += v[i]; }
    if (tid == 255){ pos[b * 2049 + 2048] = run; lds_nl = run; }
    __syncthreads();
    const int nl = lds_nl;
    #pragma unroll
    for (int i = 0; i < 8; ++i){
      int j = tid * 8 + i;
      monesC[b * 2048 + j] = (j < nl) ? (ushort_t)0x3F80 : (ushort_t)0;
    }
  } else {
    int wid = tid >> 6, lane = tid & 63;
    int n = (bid - 3188) * 4 + wid;
    float s = 0.f;
    #pragma unroll
    for (int it = 0; it < 24; ++it){
      int k = it * 64 + lane;
      s += bo[k] * Wout[(size_t)k * 512 + n];
    }
    #pragma unroll
    for (int off = 32; off; off >>= 1) s += __shfl_xor(s, off);
    if (lane == 0) bcomb[n] = s + bout[n];
  }
}

// ---------------- LayerNorm (bf16 input) ----------------

__global__ __launch_bounds__(256)
void ln_kernel(const ushort_t* __restrict__ xlb, ushort_t* __restrict__ xn,
               const float* __restrict__ gamma, const float* __restrict__ beta){
  int rid = blockIdx.x * 4 + (threadIdx.x >> 6);
  int lane = threadIdx.x & 63;
  int l = rid >> 12, bs = rid & 4095;
  const ushort_t* row = xlb + (size_t)bs * 1536 + l * 512;
  ushort_t* orow = xn + (size_t)bs * 1536 + l * 512;
  const bf16x8 a = *(const bf16x8*)(row + lane * 8);
  float vals[8];
  #pragma unroll
  for (int j = 0; j < 8; ++j) vals[j] = bf2f((ushort_t)a[j]);
  float s = 0.f, ss = 0.f;
  #pragma unroll
  for (int j = 0; j < 8; ++j){ s += vals[j]; ss += vals[j] * vals[j]; }
  #pragma unroll
  for (int off = 32; off; off >>= 1){
    s += __shfl_xor(s, off);
    ss += __shfl_xor(ss, off);
  }
  float mean = s * (1.0f / 512.0f);
  float var = ss * (1.0f / 512.0f) - mean * mean;
  float inv = rsqrtf(var + 1e-5f);
  const float* g = gamma + l * 512 + lane * 8;
  const float* be = beta + l * 512 + lane * 8;
  float4 g0 = ((const float4*)g)[0], g1 = ((const float4*)g)[1];
  float4 be0 = ((const float4*)be)[0], be1 = ((const float4*)be)[1];
  float gs[8] = {g0.x, g0.y, g0.z, g0.w, g1.x, g1.y, g1.z, g1.w};
  float bs8[8] = {be0.x, be0.y, be0.z, be0.w, be1.x, be1.y, be1.z, be1.w};
  bf16x8 r;
  #pragma unroll
  for (int j = 0; j < 8; ++j)
    r[j] = (short)f2bf((vals[j] - mean) * inv * gs[j] + bs8[j]);
  *(bf16x8*)(orow + lane * 8) = r;
}

// ---------------- Flash attention over COMPACTED keys ----------------
// Q from dense QbD [3][4096][512] (stride 512).

__global__ __launch_bounds__(256)
void attn_kernel(const ushort_t* __restrict__ QbD, const ushort_t* __restrict__ KC,
                 const ushort_t* __restrict__ VtC, const ushort_t* __restrict__ mones,
                 const int* __restrict__ pos, ushort_t* __restrict__ att){
  const int hz = blockIdx.x, qb = blockIdx.y;
  const int h = hz & 7, z = hz >> 3;
  const int l = z >> 1, b = z & 1;
  const ushort_t* Qb = QbD + ((size_t)l * 4096 + b * 2048) * 512 + h * 64;
  const ushort_t* Kb = KC + (size_t)z * 2048 * 512 + h * 64;      // [pad nlive][512]
  const ushort_t* Vt = VtC + ((size_t)(z * 8 + h) * 64) * 2048;   // [64 d][2048 k]

  const int nl = pos[b * 2049 + 2048];
  const int nt2 = (((nl + 63) >> 6) + 1) & ~1;

  __shared__ __attribute__((aligned(16))) ushort_t Ks[2][64 * 64];
  __shared__ __attribute__((aligned(16))) ushort_t Vs[2][64 * 64];

  const int tid = threadIdx.x, wid = tid >> 6, lane = tid & 63;
  const int lr = lane & 15, lk = lane >> 4;
  const int sw = lr & 7;
  const int qrow = qb * 64 + wid * 16 + lr;

  const ushort_t* qp = Qb + (size_t)qrow * 512 + lk * 8;
  const bf16x8 q0 = *(const bf16x8*)qp;
  const bf16x8 q1 = *(const bf16x8*)(qp + 32);

  const int ch0 = wid * 64 + lane, ch1 = 256 + wid * 64 + lane;
  const int r0_ = ch0 >> 3, c0_ = (ch0 & 7) ^ (r0_ & 7);
  const int r1_ = ch1 >> 3, c1_ = (ch1 & 7) ^ (r1_ & 7);
  const ushort_t* kg0 = Kb + (size_t)r0_ * 512 + c0_ * 8;
  const ushort_t* kg1 = Kb + (size_t)r1_ * 512 + c1_ * 8;
  const ushort_t* vg0 = Vt + (size_t)r0_ * 2048 + c0_ * 8;
  const ushort_t* vg1 = Vt + (size_t)r1_ * 2048 + c1_ * 8;
  ushort_t* const kdA0 = &Ks[0][(wid * 64) * 8];
  ushort_t* const kdA1 = &Ks[0][(256 + wid * 64) * 8];
  ushort_t* const kdB0 = &Ks[1][(wid * 64) * 8];
  ushort_t* const kdB1 = &Ks[1][(256 + wid * 64) * 8];
  ushort_t* const vdA0 = &Vs[0][(wid * 64) * 8];
  ushort_t* const vdA1 = &Vs[0][(256 + wid * 64) * 8];
  ushort_t* const vdB0 = &Vs[1][(wid * 64) * 8];
  ushort_t* const vdB1 = &Vs[1][(256 + wid * 64) * 8];

  const ushort_t* const kbA0 = &Ks[0][lr * 64 + (lk ^ sw) * 8];
  const ushort_t* const kbA4 = &Ks[0][lr * 64 + ((lk ^ sw) ^ 4) * 8];
  const ushort_t* const kbB0 = &Ks[1][lr * 64 + (lk ^ sw) * 8];
  const ushort_t* const kbB4 = &Ks[1][lr * 64 + ((lk ^ sw) ^ 4) * 8];
  const ushort_t* const vbA0 = &Vs[0][lr * 64 + (lk ^ sw) * 8];
  const ushort_t* const vbA4 = &Vs[0][lr * 64 + ((lk ^ sw) ^ 4) * 8];
  const ushort_t* const vbB0 = &Vs[1][lr * 64 + (lk ^ sw) * 8];
  const ushort_t* const vbB4 = &Vs[1][lr * 64 + ((lk ^ sw) ^ 4) * 8];

  const ushort_t* pm = mones + b * 2048 + lk * 8;

  f32x4 o[4] = {};
  f32x4 lrun = {0.f, 0.f, 0.f, 0.f};

  gload_lds16(kg0, kdA0); gload_lds16(kg1, kdA1);
  gload_lds16(vg0, vdA0); gload_lds16(vg1, vdA1);
  kg0 += 32768; kg1 += 32768; vg0 += 64; vg1 += 64;
  __syncthreads();

  auto tile_step = [&](const ushort_t* kb0, const ushort_t* kb4,
                       const ushort_t* vb0, const ushort_t* vb4,
                       ushort_t* sk0, ushort_t* sk1, ushort_t* sv0, ushort_t* sv1,
                       bool doStage){
    if (doStage){
      gload_lds16(kg0, sk0); gload_lds16(kg1, sk1);
      gload_lds16(vg0, sv0); gload_lds16(vg1, sv1);
      kg0 += 32768; kg1 += 32768; vg0 += 64; vg1 += 64;
    }
    const bf16x8 mo0 = *(const bf16x8*)pm;
    const bf16x8 mo1 = *(const bf16x8*)(pm + 32);
    pm += 64;

    f32x4 t[4];
    __builtin_amdgcn_s_setprio(1);
    #pragma unroll
    for (int hh = 0; hh < 4; ++hh){
      const bf16x8 kf0 = *(const bf16x8*)(kb0 + hh * 1024);
      const bf16x8 kf1 = *(const bf16x8*)(kb4 + hh * 1024);
      f32x4 tt = {0.f, 0.f, 0.f, 0.f};
      tt = __builtin_amdgcn_mfma_f32_16x16x32_bf16(kf0, q0, tt, 0, 0, 0);
      tt = __builtin_amdgcn_mfma_f32_16x16x32_bf16(kf1, q1, tt, 0, 0, 0);
      t[hh] = tt;
    }
    __builtin_amdgcn_s_setprio(0);

    unsigned a00, a01, a10, a11, a20, a21, a30, a31;
    a00 = cvt_pk_bf16(exp2_fast(t[0][0]), exp2_fast(t[0][1]));
    a01 = cvt_pk_bf16(exp2_fast(t[0][2]), exp2_fast(t[0][3]));
    a10 = cvt_pk_bf16(exp2_fast(t[1][0]), exp2_fast(t[1][1]));
    a11 = cvt_pk_bf16(exp2_fast(t[1][2]), exp2_fast(t[1][3]));
    a20 = cvt_pk_bf16(exp2_fast(t[2][0]), exp2_fast(t[2][1]));
    a21 = cvt_pk_bf16(exp2_fast(t[2][2]), exp2_fast(t[2][3]));
    a30 = cvt_pk_bf16(exp2_fast(t[3][0]), exp2_fast(t[3][1]));
    a31 = cvt_pk_bf16(exp2_fast(t[3][2]), exp2_fast(t[3][3]));
    asm("v_permlane32_swap_b32 %0, %1" : "+v"(a00), "+v"(a10));
    asm("v_permlane32_swap_b32 %0, %1" : "+v"(a01), "+v"(a11));
    asm("v_permlane32_swap_b32 %0, %1" : "+v"(a20), "+v"(a30));
    asm("v_permlane32_swap_b32 %0, %1" : "+v"(a21), "+v"(a31));
    asm("v_permlane16_swap_b32 %0, %1" : "+v"(a00), "+v"(a10));
    asm("v_permlane16_swap_b32 %0, %1" : "+v"(a01), "+v"(a11));
    asm("v_permlane16_swap_b32 %0, %1" : "+v"(a20), "+v"(a30));
    asm("v_permlane16_swap_b32 %0, %1" : "+v"(a21), "+v"(a31));
    const u32x4 f0 = {a00, a01, a10, a11};
    const u32x4 f1 = {a20, a21, a30, a31};
    const bf16x8 pf0 = __builtin_bit_cast(bf16x8, f0);
    const bf16x8 pf1 = __builtin_bit_cast(bf16x8, f1);

    __builtin_amdgcn_s_setprio(1);
    lrun = __builtin_amdgcn_mfma_f32_16x16x32_bf16(pf0, mo0, lrun, 0, 0, 0);
    lrun = __builtin_amdgcn_mfma_f32_16x16x32_bf16(pf1, mo1, lrun, 0, 0, 0);
    #pragma unroll
    for (int n = 0; n < 4; ++n){
      const bf16x8 v0 = *(const bf16x8*)(vb0 + n * 1024);
      const bf16x8 v1 = *(const bf16x8*)(vb4 + n * 1024);
      o[n] = __builtin_amdgcn_mfma_f32_16x16x32_bf16(pf0, v0, o[n], 0, 0, 0);
      o[n] = __builtin_amdgcn_mfma_f32_16x16x32_bf16(pf1, v1, o[n], 0, 0, 0);
    }
    __builtin_amdgcn_s_setprio(0);
    __syncthreads();
  };

  for (int kt2 = 0; kt2 < nt2; kt2 += 2){
    tile_step(kbA0, kbA4, vbA0, vbA4, kdB0, kdB1, vdB0, vdB1, true);
    tile_step(kbB0, kbB4, vbB0, vbB4, kdA0, kdA1, vdA0, vdA1, kt2 + 2 < nt2);
  }

  float invj[4];
  #pragma unroll
  for (int j = 0; j < 4; ++j) invj[j] = 1.0f / lrun[j];
  const size_t arow0 = (size_t)(b * 2048 + qb * 64 + wid * 16);
  #pragma unroll
  for (int n = 0; n < 4; ++n)
    #pragma unroll
    for (int j = 0; j < 4; ++j)
      att[(arow0 + lk * 4 + j) * 1536 + l * 512 + h * 64 + n * 16 + lr] = f2bf(o[n][j] * invj[j]);
}

// ---------------- launch ----------------

extern "C" void kernel_launch(void* const* d_in, const int* in_sizes, int n_in,
                              void* d_out, int out_size, void* d_ws, size_t ws_size,
                              hipStream_t stream){
  const float* x    = (const float*)d_in[0];
  const int*   mask = (const int*)d_in[1];
  const float* Wp   = (const float*)d_in[2];
  const float* bp   = (const float*)d_in[3];
  const float* gamma= (const float*)d_in[4];
  const float* beta = (const float*)d_in[5];
  const float* Wq   = (const float*)d_in[6];
  const float* bq   = (const float*)d_in[7];
  const float* Wk   = (const float*)d_in[8];
  const float* bk   = (const float*)d_in[9];
  const float* Wv   = (const float*)d_in[10];
  const float* bv   = (const float*)d_in[11];
  const float* Wo   = (const float*)d_in[12];
  const float* bo   = (const float*)d_in[13];
  const float* Wout = (const float*)d_in[14];
  const float* bout = (const float*)d_in[15];

  char* ws = (char*)d_ws;
  size_t off = 0;
  auto alloc = [&](size_t bytes){ void* p = ws + off; off += (bytes + 255) & ~(size_t)255; return p; };
  ushort_t* xb    = (ushort_t*)alloc(4096ull * 512 * 2);
  ushort_t* WpT   = (ushort_t*)alloc(1536ull * 512 * 2);
  ushort_t* WqkvT = (ushort_t*)alloc(3ull * 1536 * 512 * 2);
  ushort_t* WoB   = (ushort_t*)alloc(3ull * 512 * 512 * 2);
  ushort_t* WoutT = (ushort_t*)alloc(512ull * 1536 * 2);
  ushort_t* WcombT= (ushort_t*)alloc(512ull * 1536 * 2);
  float*    bqkv  = (float*)alloc(3ull * 1536 * 4);
  float*    zbias = (float*)alloc(512ull * 4);
  float*    bcomb = (float*)alloc(512ull * 4);
  ushort_t* monesC= (ushort_t*)alloc(4096ull * 2);
  int*      pos   = (int*)alloc(2ull * 2049 * 4);
  char*     xlbuf = (char*)alloc(4096ull * 1536 * 4);          // 25.17 MB scratch
  ushort_t* xn    = (ushort_t*)alloc(4096ull * 1536 * 2);
  ushort_t* QbD   = (ushort_t*)alloc(3ull * 4096 * 512 * 2);   // dense Q
  ushort_t* VtD   = (ushort_t*)alloc(6ull * 512 * 2048 * 2);   // dense V^T
  ushort_t* KC    = (ushort_t*)alloc(6ull * 2048 * 512 * 2);   // compacted K
  // xlbuf: xlb (bf16, 12.58 MB) lives until ln; then att + VtC reuse the region.
  ushort_t* xlb   = (ushort_t*)xlbuf;
  ushort_t* att   = (ushort_t*)xlbuf;
  ushort_t* VtC   = (ushort_t*)(xlbuf + 12582912);

  // dispatch 1: prep-A (4354 blocks) — only gemm_dual's inputs
  prep_kernel<<<4354, 256, 0, stream>>>(x, Wo, Wp, Wout,
                                        xb, WoB, WpT, WoutT, zbias);

  // dispatch 2: Wcomb GEMM + xl GEMM + Wq/Wk/Wv transposes + bqkv + scan + bcomb
  gemm_dual<<<3316, 256, 0, stream>>>(WoutT, WoB, zbias, WcombT, xb, WpT, bp, xlb,
                                      Wq, Wk, Wv, WqkvT, bq, bk, bv, bqkv,
                                      mask, monesC, pos, bo, Wout, bout, bcomb);

  // LayerNorm (bf16 in) -> xn bf16
  ln_kernel<<<3072, 256, 0, stream>>>(xlb, xn, gamma, beta);
  // qkv GEMM; Q -> QbD (dense), K vector-scattered compacted -> KC, V -> VtD
  gemm_bt<1, 64, 1><<<dim3(24, 32, 3), 256, 0, stream>>>(xn, WqkvT, bqkv, QbD,
      4096, 1536, 512, 1536, 512, 512, 512, 786432, 4096ll * 512, 1536,
      VtD, KC, pos);
  // V-gather live cols -> VtC; zero K/V pads (774 blocks)
  compact_kernel<<<dim3(129, 6), 256, 0, stream>>>(VtD, pos, KC, VtC);
  // flash attention over compacted keys
  attn_kernel<<<dim3(48, 32, 1), 256, 0, stream>>>(QbD, KC, VtC, monesC, pos, att);
  // out = att @ Wcomb_stack + bcomb   fp32 [4096][512]
  gemm_bt<0, 32, 0><<<dim3(16, 32, 1), 256, 0, stream>>>(att, WcombT, bcomb, (float*)d_out,
      4096, 512, 1536, 1536, 1536, 512, 0, 0, 0, 0, nullptr, nullptr, nullptr);
}